// Round 12
// baseline (753.305 us; speedup 1.0000x reference)
//
#include <hip/hip_runtime.h>
#include <stdint.h>

#define DIM 512
#define NHEAD 16
#define HEADD 32
#define BATCH 16
#define SEQL 2304
#define XROWS (BATCH*SEQL)        // 36864
#define NROWS (XROWS + BATCH)     // 36880
#define ATT_SCALE 0.17677669529663687f

typedef __attribute__((ext_vector_type(8))) short short8;
typedef __attribute__((ext_vector_type(4))) float f32x4;

__device__ __forceinline__ float bf2f(unsigned short v) {
    union { unsigned u; float f; } t; t.u = ((unsigned)v) << 16; return t.f;
}
__device__ __forceinline__ unsigned short f2bf(float f) {
    union { float f; unsigned u; } t; t.f = f;
    unsigned r = t.u + 0x7fffu + ((t.u >> 16) & 1u);
    return (unsigned short)(r >> 16);
}
__device__ __forceinline__ void unpack8(const int4 c, float* o) {
    union { unsigned u; float f; } t;
    unsigned w0 = (unsigned)c.x, w1 = (unsigned)c.y, w2 = (unsigned)c.z, w3 = (unsigned)c.w;
    t.u = w0 << 16;         o[0] = t.f;
    t.u = w0 & 0xffff0000u; o[1] = t.f;
    t.u = w1 << 16;         o[2] = t.f;
    t.u = w1 & 0xffff0000u; o[3] = t.f;
    t.u = w2 << 16;         o[4] = t.f;
    t.u = w2 & 0xffff0000u; o[5] = t.f;
    t.u = w3 << 16;         o[6] = t.f;
    t.u = w3 & 0xffff0000u; o[7] = t.f;
}
__device__ __forceinline__ void gl_lds16(const void* g, void* l) {
    __builtin_amdgcn_global_load_lds((const __attribute__((address_space(1))) unsigned int*)g,
                                     (__attribute__((address_space(3))) unsigned int*)l,
                                     16, 0, 0);
}

// Branch-free exact-precision GELU: erf via Abramowitz-Stegun 7.1.26 (|err| <= 1.5e-7).
__device__ __forceinline__ float gelu_exact(float v) {
    union { float f; unsigned u; } zc; zc.f = v * 0.70710678118654752f;  // z = v/sqrt(2)
    unsigned sgn = zc.u & 0x80000000u;
    union { float f; unsigned u; } az; az.u = zc.u & 0x7fffffffu;        // |z|
    float t  = __builtin_amdgcn_rcpf(fmaf(0.3275911f, az.f, 1.0f));
    float p  = t * fmaf(t, fmaf(t, fmaf(t, fmaf(t, 1.061405429f, -1.453152027f),
                                        1.421413741f), -0.284496736f), 0.254829592f);
    float e  = __expf(-az.f * az.f);
    union { float f; unsigned u; } er; er.f = fmaf(-p, e, 1.0f);         // erf(|z|)
    er.u |= sgn;                                                         // erf(z)
    return 0.5f * v * (1.0f + er.f);
}

// LayerNorm for one 512-elem row: one wave, bf16 output.
__device__ __forceinline__ void ln_row(const float* __restrict__ src, int lane,
                                       const float* __restrict__ g, const float* __restrict__ be,
                                       unsigned short* __restrict__ outrow) {
    int c0 = lane * 8;
    float4 v0 = *(const float4*)(src + c0);
    float4 v1 = *(const float4*)(src + c0 + 4);
    float s = v0.x+v0.y+v0.z+v0.w + v1.x+v1.y+v1.z+v1.w;
    float q = v0.x*v0.x+v0.y*v0.y+v0.z*v0.z+v0.w*v0.w + v1.x*v1.x+v1.y*v1.y+v1.z*v1.z+v1.w*v1.w;
    for (int m = 1; m < 64; m <<= 1) { s += __shfl_xor(s, m); q += __shfl_xor(q, m); }
    float mean = s * (1.0f/512.0f);
    float var  = q * (1.0f/512.0f) - mean*mean;
    float rs = rsqrtf(var + 1e-3f);
    float4 g0 = *(const float4*)(g + c0);
    float4 g1 = *(const float4*)(g + c0 + 4);
    float4 b0 = *(const float4*)(be + c0);
    float4 b1 = *(const float4*)(be + c0 + 4);
    unsigned short o[8];
    o[0] = f2bf((v0.x-mean)*rs*g0.x + b0.x);
    o[1] = f2bf((v0.y-mean)*rs*g0.y + b0.y);
    o[2] = f2bf((v0.z-mean)*rs*g0.z + b0.z);
    o[3] = f2bf((v0.w-mean)*rs*g0.w + b0.w);
    o[4] = f2bf((v1.x-mean)*rs*g1.x + b1.x);
    o[5] = f2bf((v1.y-mean)*rs*g1.y + b1.y);
    o[6] = f2bf((v1.z-mean)*rs*g1.z + b1.z);
    o[7] = f2bf((v1.w-mean)*rs*g1.w + b1.w);
    *(int4*)(outrow + c0) = *(const int4*)o;
}

// ---------------- prep: weight transposes || bias/rel-bias pack || LN1 -------------------
#define TPOSE_BLKS 2816
#define SPACK_BLKS 90
#define LN1_BLKS   9220
__global__ __launch_bounds__(256) void prep_kernel(const float* __restrict__ w_q,
                                                   const float* __restrict__ w_kv,
                                                   const float* __restrict__ w_fc1,
                                                   const float* __restrict__ w_fc2,
                                                   unsigned short* __restrict__ Wqkv_t,
                                                   unsigned short* __restrict__ Wfc1_t,
                                                   unsigned short* __restrict__ Wfc2_t,
                                                   const float* __restrict__ b_q,
                                                   const float* __restrict__ b_kv,
                                                   const float* __restrict__ rel_table,
                                                   float* __restrict__ bqkv,
                                                   float* __restrict__ bias_exp,
                                                   const float* __restrict__ x,
                                                   const float* __restrict__ xavg,
                                                   const float* __restrict__ g1,
                                                   const float* __restrict__ be1,
                                                   unsigned short* __restrict__ xn) {
    __shared__ float tile[32][33];
    int blk = blockIdx.x;
    if (blk < TPOSE_BLKS) {
        int t = blk;
        const float* src; unsigned short* dst;
        int Kd, Nd, rowOff, tk;
        if (t < 256)        { src = w_q;   dst = Wqkv_t; Kd = 512;  Nd = 512;  rowOff = 0;   tk = 16; }
        else if (t < 768)   { t -= 256;  src = w_kv;  dst = Wqkv_t; Kd = 512;  Nd = 1024; rowOff = 512; tk = 16; }
        else if (t < 1792)  { t -= 768;  src = w_fc1; dst = Wfc1_t; Kd = 512;  Nd = 2048; rowOff = 0;   tk = 16; }
        else                { t -= 1792; src = w_fc2; dst = Wfc2_t; Kd = 2048; Nd = 512;  rowOff = 0;   tk = 64; }
        int k0 = (t % tk) * 32;
        int n0 = (t / tk) * 32;
        int tx = threadIdx.x & 31, ty = threadIdx.x >> 5;
        #pragma unroll
        for (int r = 0; r < 32; r += 8)
            tile[r + ty][tx] = src[(long)(k0 + r + ty) * Nd + n0 + tx];
        __syncthreads();
        #pragma unroll
        for (int r = 0; r < 32; r += 8)
            dst[(long)(rowOff + n0 + r + ty) * Kd + k0 + tx] = f2bf(tile[tx][r + ty]);
        return;
    }
    blk -= TPOSE_BLKS;
    if (blk < SPACK_BLKS) {
        int i = blk * 256 + threadIdx.x;
        if (i < 1536) { bqkv[i] = (i < 512) ? b_q[i] : b_kv[i - 512]; return; }
        i -= 1536;
        if (i < NHEAD*36*37) {                    // bias_exp[h][qi][j]
            int h = i / (36*37); int rem = i % (36*37); int qi = rem / 37; int j = rem % 37;
            int c0m = qi % 6, c1m = qi / 6;
            int c0n = (j < 36) ? (j % 6) : 0;
            int c1n = (j < 36) ? (j / 6) : 0;
            int id = (c0m - c0n + 5) * 11 + (c1m - c1n + 5);
            bias_exp[i] = rel_table[id * NHEAD + h];
        }
        return;
    }
    blk -= SPACK_BLKS;
    int wv = threadIdx.x >> 6, lane = threadIdx.x & 63;
    int r = blk * 4 + wv;
    if (r >= NROWS) return;
    const float* src = (r < XROWS) ? (x + (long)r * DIM) : (xavg + (long)(r - XROWS) * DIM);
    ln_row(src, lane, g1, be1, xn + (long)r * DIM);
}

// ---------------- LN2: one wave per row -------------------------------------------------
__global__ __launch_bounds__(256) void ln_kernel(const float* __restrict__ p1,
                                                 const float* __restrict__ g, const float* __restrict__ be,
                                                 unsigned short* __restrict__ out, int nrows) {
    int wv = threadIdx.x >> 6, lane = threadIdx.x & 63;
    int r = blockIdx.x * 4 + wv;
    if (r >= nrows) return;
    ln_row(p1 + (long)r * DIM, lane, g, be, out + (long)r * DIM);
}

// ---------------- bf16 MFMA GEMM: round-2 K-loop; epilogue templated per output ---------
// 128x128 tile, BK=64, single-buffered 32 KB LDS, two __syncthreads per K-step.
// K-loop CLOSED (rounds 3-9 ablation). Epilogue (round 10-11 A/B): LDS-coalesced path
// pays for bf16 scatter stores (QKV/FC1), hurts f32 path (FC2: +8 barriers, no VMEM
// gain) -> LDS_EPI template flag.
template<bool GELU_ACT, bool OUT_BF16, bool HAS_RES, bool LDS_EPI>
__global__ __launch_bounds__(256) void gemm_kernel(const short* __restrict__ A,
                                                   const short* __restrict__ Bt,
                                                   const float* __restrict__ bias,
                                                   void* __restrict__ Cout,
                                                   const float* __restrict__ Res,
                                                   int M, int N, int K, int nbx) {
    __shared__ short lds[2 * 128 * 64];        // 32 KB: a | b during K-loop; C-tile after
    short* lds_a = lds;
    short* lds_b = lds + 128 * 64;
    const int tid = threadIdx.x;
    const int lane = tid & 63;
    const int wv = tid >> 6;

    const int nwg = gridDim.x;
    const int orig = blockIdx.x;
    const int q = nwg >> 3, r = nwg & 7;
    const int xcd = orig & 7, lid = orig >> 3;
    const int wg = (xcd < r ? xcd * (q + 1) : r * (q + 1) + (xcd - r) * q) + lid;
    const int m0 = (wg / nbx) * 128;
    const int n0 = (wg % nbx) * 128;
    const int wm = (wv >> 1) * 64;
    const int wn = (wv & 1) * 64;

    f32x4 acc[4][4];
    #pragma unroll
    for (int i = 0; i < 4; i++)
        #pragma unroll
        for (int j = 0; j < 4; j++) { acc[i][j][0]=0.f; acc[i][j][1]=0.f; acc[i][j][2]=0.f; acc[i][j][3]=0.f; }

    const int srow = tid >> 3;                 // 0..31
    const int msl  = (tid & 7) ^ (srow & 7);
    const short* Aa = A + (long)(m0 + srow) * K + msl * 8;
    const short* Bb = Bt + (long)(n0 + srow) * K + msl * 8;
    short* la = lds_a + tid * 8;
    short* lb = lds_b + tid * 8;

    const int quad = lane >> 4;
    const int l15 = lane & 15;
    const short* ra0 = lds_a + (wm + l15) * 64 + ((quad)     ^ (l15 & 7)) * 8;
    const short* ra1 = lds_a + (wm + l15) * 64 + ((4 + quad) ^ (l15 & 7)) * 8;
    const short* rb0 = lds_b + (wn + l15) * 64 + ((quad)     ^ (l15 & 7)) * 8;
    const short* rb1 = lds_b + (wn + l15) * 64 + ((4 + quad) ^ (l15 & 7)) * 8;

    for (int k0 = 0; k0 < K; k0 += 64) {
        __syncthreads();
        #pragma unroll
        for (int i = 0; i < 4; i++) {
            gl_lds16(Aa + (long)(i * 32) * K + k0, la + i * 256 * 8);
            gl_lds16(Bb + (long)(i * 32) * K + k0, lb + i * 256 * 8);
        }
        __syncthreads();
        short8 af[4], bf4[4];
        #pragma unroll
        for (int mt = 0; mt < 4; mt++) af[mt] = *(const short8*)(ra0 + mt * 16 * 64);
        #pragma unroll
        for (int nt = 0; nt < 4; nt++) bf4[nt] = *(const short8*)(rb0 + nt * 16 * 64);
        #pragma unroll
        for (int mt = 0; mt < 4; mt++)
            #pragma unroll
            for (int nt = 0; nt < 4; nt++)
                acc[mt][nt] = __builtin_amdgcn_mfma_f32_16x16x32_bf16(af[mt], bf4[nt], acc[mt][nt], 0, 0, 0);
        #pragma unroll
        for (int mt = 0; mt < 4; mt++) af[mt] = *(const short8*)(ra1 + mt * 16 * 64);
        #pragma unroll
        for (int nt = 0; nt < 4; nt++) bf4[nt] = *(const short8*)(rb1 + nt * 16 * 64);
        #pragma unroll
        for (int mt = 0; mt < 4; mt++)
            #pragma unroll
            for (int nt = 0; nt < 4; nt++)
                acc[mt][nt] = __builtin_amdgcn_mfma_f32_16x16x32_bf16(af[mt], bf4[nt], acc[mt][nt], 0, 0, 0);
    }

    if (LDS_EPI) {
        // LDS-coalesced C write (pays for bf16 scatter outputs)
        float* ctile = (float*)lds;                 // 32 rows x stride 132 f32
        const int lrow_w = ((wv >> 1) << 4) + quad * 4;
        const int col_w  = ((wv & 1) << 6) + l15;
        const int lrow_r = tid >> 3;
        const int cg     = tid & 7;
        const int sub    = lrow_r & 15, half = lrow_r >> 4;
        float bv[16];
        #pragma unroll
        for (int i = 0; i < 4; i++)
            *(float4*)(bv + i * 4) = *(const float4*)(bias + n0 + cg * 16 + i * 4);

        #pragma unroll
        for (int mt = 0; mt < 4; mt++) {
            __syncthreads();
            #pragma unroll
            for (int nt = 0; nt < 4; nt++)
                #pragma unroll
                for (int r2 = 0; r2 < 4; r2++)
                    ctile[(lrow_w + r2) * 132 + col_w + nt * 16] = acc[mt][nt][r2];
            __syncthreads();
            int grow = m0 + half * 64 + mt * 16 + sub;
            if (grow < M) {
                int gcol = n0 + cg * 16;
                float v[16];
                #pragma unroll
                for (int i = 0; i < 4; i++)
                    *(float4*)(v + i * 4) = *(const float4*)(ctile + lrow_r * 132 + cg * 16 + i * 4);
                float rv[16];
                if (HAS_RES) {
                    #pragma unroll
                    for (int i = 0; i < 4; i++)
                        *(float4*)(rv + i * 4) = *(const float4*)(Res + (long)grow * N + gcol + i * 4);
                }
                if (OUT_BF16) {
                    unsigned short ob[16];
                    #pragma unroll
                    for (int i = 0; i < 16; i++) {
                        float vv = v[i] + bv[i];
                        if (GELU_ACT) vv = gelu_exact(vv);
                        if (HAS_RES) vv += rv[i];
                        ob[i] = f2bf(vv);
                    }
                    unsigned short* dst = (unsigned short*)Cout + (long)grow * N + gcol;
                    *(int4*)dst       = *(const int4*)ob;
                    *(int4*)(dst + 8) = *(const int4*)(ob + 8);
                } else {
                    float* dst = (float*)Cout + (long)grow * N + gcol;
                    #pragma unroll
                    for (int i = 0; i < 4; i++) {
                        float4 ov;
                        float* vp = v + i * 4;
                        float* rp = rv + i * 4;
                        ov.x = vp[0] + bv[i*4+0]; ov.y = vp[1] + bv[i*4+1];
                        ov.z = vp[2] + bv[i*4+2]; ov.w = vp[3] + bv[i*4+3];
                        if (GELU_ACT) { ov.x = gelu_exact(ov.x); ov.y = gelu_exact(ov.y);
                                        ov.z = gelu_exact(ov.z); ov.w = gelu_exact(ov.w); }
                        if (HAS_RES) { ov.x += rp[0]; ov.y += rp[1]; ov.z += rp[2]; ov.w += rp[3]; }
                        *(float4*)(dst + i * 4) = ov;
                    }
                }
            }
        }
    } else {
        // direct fragment-order epilogue (best for f32 outputs — round 8/10 measured)
        #pragma unroll
        for (int mt = 0; mt < 4; mt++) {
            int rbase = m0 + wm + mt * 16 + quad * 4;
            #pragma unroll
            for (int nt = 0; nt < 4; nt++) {
                int col = n0 + wn + nt * 16 + l15;
                float bv = bias[col];
                #pragma unroll
                for (int r2 = 0; r2 < 4; r2++) {
                    int row = rbase + r2;
                    if (row < M) {
                        float v = acc[mt][nt][r2] + bv;
                        if (GELU_ACT) v = gelu_exact(v);
                        if (HAS_RES) v += Res[(long)row * N + col];
                        if (OUT_BF16) ((unsigned short*)Cout)[(long)row * N + col] = f2bf(v);
                        else          ((float*)Cout)[(long)row * N + col] = v;
                    }
                }
            }
        }
    }
}

// ---------------- attention: MFMA windowed (blocks 0..8191) || global-token (8192+) -----
// 128-thread blocks (2 waves): LDS 20.4 KB -> 7 blocks/CU = 14 waves/CU (was 12 at
// 4-wave/41 KB) for better latency overlap. s_setprio(1) around MFMA clusters
// (m191-verified +4-7% for independent-wave attention blocks).
__global__ __launch_bounds__(128) void attn_kernel(const short* __restrict__ qkv,
                                                   const float* __restrict__ bias_exp,
                                                   const float* __restrict__ xin,
                                                   const float* __restrict__ xavg,
                                                   float* __restrict__ XALL) {
    __shared__ short vt[2][32 * 64];   // VT[d][j] bf16 (j padded to 64)
    __shared__ short pl[2][48 * 64];   // P[qi][j] bf16 (qi padded 48, j padded 64)
    __shared__ float sums[2][48];      // 1/rowsum per qi
    const int tid = threadIdx.x;
    if (blockIdx.x < 8192) {
        const int wv = tid >> 6;
        const int lane = tid & 63;
        const int gw = blockIdx.x * 2 + wv;            // global wave = (win, head)
        const int win = gw >> 4;
        const int h = gw & 15;
        const int b = win >> 6;
        const int i1 = (win >> 3) & 7;
        const int i3 = win & 7;
        short* VT = vt[wv];
        short* PL = pl[wv];
        float* SM = sums[wv];
        const int quad = lane >> 4;
        const int l15 = lane & 15;

        // zero-fill VT + PL pads
        {
            int4 z; z.x = 0; z.y = 0; z.z = 0; z.w = 0;
            int4* v4 = (int4*)VT;
            #pragma unroll
            for (int i = 0; i < 4; i++) v4[lane + 64 * i] = z;
            int4* p4 = (int4*)PL;
            #pragma unroll
            for (int i = 0; i < 6; i++) p4[lane + 64 * i] = z;
        }
        // stage V transposed, lane-per-column: lane j owns column j (conflict-free)
        if (lane < 37) {
            long grow;
            if (lane < 36) { int i2 = lane / 6, i4 = lane % 6; grow = (long)b * SEQL + (i1*6 + i2) * 48 + i3*6 + i4; }
            else grow = XROWS + b;
            const int4* vp = (const int4*)(qkv + grow * 1536 + 1024 + h * 32);
            int4 r0 = vp[0], r1 = vp[1], r2v = vp[2], r3 = vp[3];
            const unsigned short* u0 = (const unsigned short*)&r0;
            const unsigned short* u1 = (const unsigned short*)&r1;
            const unsigned short* u2 = (const unsigned short*)&r2v;
            const unsigned short* u3 = (const unsigned short*)&r3;
            #pragma unroll
            for (int t = 0; t < 8; t++) VT[t * 64 + lane]        = (short)u0[t];
            #pragma unroll
            for (int t = 0; t < 8; t++) VT[(8 + t) * 64 + lane]  = (short)u1[t];
            #pragma unroll
            for (int t = 0; t < 8; t++) VT[(16 + t) * 64 + lane] = (short)u2[t];
            #pragma unroll
            for (int t = 0; t < 8; t++) VT[(24 + t) * 64 + lane] = (short)u3[t];
        }
        __syncthreads();

        // A-frags (Q rows) and B-frags (K rows) directly from global (L2-hot)
        short8 qf[3], kf[3];
        #pragma unroll
        for (int tm = 0; tm < 3; tm++) {
            int qi = tm * 16 + l15;
            if (qi < 36) {
                int i2 = qi / 6, i4 = qi % 6;
                long grow = (long)b * SEQL + (i1*6 + i2) * 48 + i3*6 + i4;
                qf[tm] = *(const short8*)(qkv + grow * 1536 + h * 32 + quad * 8);
            } else {
                #pragma unroll
                for (int i = 0; i < 8; i++) qf[tm][i] = 0;
            }
        }
        #pragma unroll
        for (int tn = 0; tn < 3; tn++) {
            int j = tn * 16 + l15;
            if (j <= 36) {
                long grow;
                if (j < 36) { int i2 = j / 6, i4 = j % 6; grow = (long)b * SEQL + (i1*6 + i2) * 48 + i3*6 + i4; }
                else grow = XROWS + b;
                kf[tn] = *(const short8*)(qkv + grow * 1536 + 512 + h * 32 + quad * 8);
            } else {
                #pragma unroll
                for (int i = 0; i < 8; i++) kf[tn][i] = 0;
            }
        }
        // S = Q·K^T : 9 MFMAs
        f32x4 s[3][3];
        __builtin_amdgcn_s_setprio(1);
        #pragma unroll
        for (int tm = 0; tm < 3; tm++)
            #pragma unroll
            for (int tn = 0; tn < 3; tn++) {
                f32x4 z; z[0]=0.f; z[1]=0.f; z[2]=0.f; z[3]=0.f;
                s[tm][tn] = __builtin_amdgcn_mfma_f32_16x16x32_bf16(qf[tm], kf[tn], z, 0, 0, 0);
            }
        __builtin_amdgcn_s_setprio(0);
        // scale + bias + pad mask
        #pragma unroll
        for (int tm = 0; tm < 3; tm++)
            #pragma unroll
            for (int r = 0; r < 4; r++) {
                int qi = tm * 16 + quad * 4 + r;
                const float* bh = bias_exp + h * (36*37) + (qi < 36 ? qi : 35) * 37;
                #pragma unroll
                for (int tn = 0; tn < 3; tn++) {
                    int j = tn * 16 + l15;
                    float bv = bh[j <= 36 ? j : 36];
                    float v = fmaf(s[tm][tn][r], ATT_SCALE, bv);
                    s[tm][tn][r] = (j <= 36) ? v : -1e30f;
                }
            }
        // row softmax
        #pragma unroll
        for (int tm = 0; tm < 3; tm++)
            #pragma unroll
            for (int r = 0; r < 4; r++) {
                float mx = fmaxf(fmaxf(s[tm][0][r], s[tm][1][r]), s[tm][2][r]);
                for (int m = 1; m < 16; m <<= 1) mx = fmaxf(mx, __shfl_xor(mx, m));
                float e0 = __expf(s[tm][0][r] - mx);
                float e1 = __expf(s[tm][1][r] - mx);
                float e2 = __expf(s[tm][2][r] - mx);
                float sum = e0 + e1 + e2;
                for (int m = 1; m < 16; m <<= 1) sum += __shfl_xor(sum, m);
                s[tm][0][r] = e0; s[tm][1][r] = e1; s[tm][2][r] = e2;
                if (l15 == 0) SM[tm * 16 + quad * 4 + r] = 1.0f / sum;
            }
        // P -> LDS (bf16), row-major [qi][j]
        #pragma unroll
        for (int tm = 0; tm < 3; tm++)
            #pragma unroll
            for (int r = 0; r < 4; r++) {
                int row = (tm * 16 + quad * 4 + r) * 64;
                #pragma unroll
                for (int tn = 0; tn < 3; tn++)
                    PL[row + tn * 16 + l15] = (short)f2bf(s[tm][tn][r]);
            }
        // PV: O^T(32x48) = VT(32x64) · P^T(64x48) : 12 MFMAs over 2 K-chunks
        f32x4 o[2][3];
        #pragma unroll
        for (int i = 0; i < 2; i++)
            #pragma unroll
            for (int j = 0; j < 3; j++) { o[i][j][0]=0.f; o[i][j][1]=0.f; o[i][j][2]=0.f; o[i][j][3]=0.f; }
        #pragma unroll
        for (int ch = 0; ch < 2; ch++) {
            short8 va[2], pb[3];
            #pragma unroll
            for (int tmd = 0; tmd < 2; tmd++)
                va[tmd] = *(const short8*)(VT + (tmd * 16 + l15) * 64 + ch * 32 + quad * 8);
            #pragma unroll
            for (int tnq = 0; tnq < 3; tnq++)
                pb[tnq] = *(const short8*)(PL + (tnq * 16 + l15) * 64 + ch * 32 + quad * 8);
            __builtin_amdgcn_s_setprio(1);
            #pragma unroll
            for (int tmd = 0; tmd < 2; tmd++)
                #pragma unroll
                for (int tnq = 0; tnq < 3; tnq++)
                    o[tmd][tnq] = __builtin_amdgcn_mfma_f32_16x16x32_bf16(va[tmd], pb[tnq], o[tmd][tnq], 0, 0, 0);
            __builtin_amdgcn_s_setprio(0);
        }
        // epilogue: lane holds col qi = tnq*16+l15, rows d = tmd*16+quad*4+r
        #pragma unroll
        for (int tnq = 0; tnq < 3; tnq++) {
            int qi = tnq * 16 + l15;
            if (qi >= 36) continue;
            int i2 = qi / 6, i4 = qi % 6;
            long growq = (long)b * SEQL + (i1*6 + i2) * 48 + i3*6 + i4;
            float is = SM[qi];
            #pragma unroll
            for (int tmd = 0; tmd < 2; tmd++) {
                long base = growq * DIM + h * 32 + tmd * 16 + quad * 4;
                float4 xv = *(const float4*)(xin + base);
                float4 ov;
                ov.x = xv.x + o[tmd][tnq][0] * is;
                ov.y = xv.y + o[tmd][tnq][1] * is;
                ov.z = xv.z + o[tmd][tnq][2] * is;
                ov.w = xv.w + o[tmd][tnq][3] * is;
                *(float4*)(XALL + base) = ov;
            }
        }
        return;
    }
    // ---- global-token attention: 1 block (128 thr, 2 waves) per (batch, head) ----
    {
        const int bb = blockIdx.x - 8192;
        const int b = bb >> 4;
        const int h = bb & 15;
        __shared__ float qs[32];
        __shared__ float redm[2], redsum[2];
        __shared__ float wout[2][32];
        if (tid < 32) qs[tid] = bf2f(((const unsigned short*)qkv)[(long)(XROWS + b) * 1536 + h * 32 + tid]);
        __syncthreads();
        float qr[32];
        #pragma unroll
        for (int d = 0; d < 32; d++) qr[d] = qs[d];
        float s[18];
        float mx = -1e30f;
        #pragma unroll
        for (int i = 0; i < 18; i++) {
            int t = tid + i * 128;
            const int4* kp = (const int4*)(qkv + (long)(b * SEQL + t) * 1536 + 512 + h * 32);
            float kr[32];
            unpack8(kp[0], kr); unpack8(kp[1], kr + 8); unpack8(kp[2], kr + 16); unpack8(kp[3], kr + 24);
            float d0 = 0.f, d1 = 0.f, d2 = 0.f, d3 = 0.f;
            #pragma unroll
            for (int dd = 0; dd < 8; dd++) {
                d0 += qr[dd] * kr[dd]; d1 += qr[8+dd] * kr[8+dd];
                d2 += qr[16+dd] * kr[16+dd]; d3 += qr[24+dd] * kr[24+dd];
            }
            s[i] = (d0 + d1 + d2 + d3) * ATT_SCALE;
            mx = fmaxf(mx, s[i]);
        }
        for (int m = 1; m < 64; m <<= 1) mx = fmaxf(mx, __shfl_xor(mx, m));
        if ((tid & 63) == 0) redm[tid >> 6] = mx;
        __syncthreads();
        mx = fmaxf(redm[0], redm[1]);
        float sum = 0.f;
        #pragma unroll
        for (int i = 0; i < 18; i++) { s[i] = __expf(s[i] - mx); sum += s[i]; }
        for (int m = 1; m < 64; m <<= 1) sum += __shfl_xor(sum, m);
        if ((tid & 63) == 0) redsum[tid >> 6] = sum;
        __syncthreads();
        sum = redsum[0] + redsum[1];
        float o[32];
        #pragma unroll
        for (int d = 0; d < 32; d++) o[d] = 0.f;
        #pragma unroll
        for (int i = 0; i < 18; i++) {
            int t = tid + i * 128;
            const int4* vp = (const int4*)(qkv + (long)(b * SEQL + t) * 1536 + 1024 + h * 32);
            float vr[32];
            unpack8(vp[0], vr); unpack8(vp[1], vr + 8); unpack8(vp[2], vr + 16); unpack8(vp[3], vr + 24);
            float p = s[i];
            #pragma unroll
            for (int d = 0; d < 32; d++) o[d] += p * vr[d];
        }
        for (int m = 1; m < 64; m <<= 1) {
            #pragma unroll
            for (int d = 0; d < 32; d++) o[d] += __shfl_xor(o[d], m);
        }
        if ((tid & 63) == 0) {
            #pragma unroll
            for (int d = 0; d < 32; d++) wout[tid >> 6][d] = o[d];
        }
        __syncthreads();
        if (tid < 32) {
            float t = wout[0][tid] + wout[1][tid];
            XALL[(long)(XROWS + b) * DIM + h * 32 + tid] = xavg[b * DIM + h * 32 + tid] + t / sum;
        }
    }
}

// ---------------- launch --------------------------------------------------------------
extern "C" void kernel_launch(void* const* d_in, const int* in_sizes, int n_in,
                              void* d_out, int out_size, void* d_ws, size_t ws_size,
                              hipStream_t stream) {
    const float* x      = (const float*)d_in[0];
    const float* xavg   = (const float*)d_in[1];
    const float* w_kv   = (const float*)d_in[2];
    const float* b_kv   = (const float*)d_in[3];
    const float* w_q    = (const float*)d_in[4];
    const float* b_q    = (const float*)d_in[5];
    const float* rel    = (const float*)d_in[6];
    const float* g1     = (const float*)d_in[7];
    const float* be1    = (const float*)d_in[8];
    const float* g2     = (const float*)d_in[9];
    const float* be2    = (const float*)d_in[10];
    const float* w_fc1  = (const float*)d_in[11];
    const float* b_fc1  = (const float*)d_in[12];
    const float* w_fc2  = (const float*)d_in[13];
    const float* b_fc2  = (const float*)d_in[14];

    char* ws = (char*)d_ws;
    size_t off = 0;
    auto alloc = [&](size_t bytes) { void* p = ws + off; off += (bytes + 255) & ~(size_t)255; return p; };
    short* qkv_h          = (short*)alloc((size_t)NROWS * 2048 * 2);   // qkv (1536 cols), then MLP hidden (2048 cols)
    float* XALL           = (float*)alloc((size_t)NROWS * 512 * 4);    // attn + residual, f32
    short* xn             = (short*)alloc((size_t)NROWS * 512 * 2);    // LN output, bf16 (reused LN1/LN2)
    unsigned short* Wqkv_t = (unsigned short*)alloc((size_t)1536 * 512 * 2);
    unsigned short* Wfc1_t = (unsigned short*)alloc((size_t)2048 * 512 * 2);
    unsigned short* Wfc2_t = (unsigned short*)alloc((size_t)512 * 2048 * 2);
    float* bqkv           = (float*)alloc(1536 * 4);
    float* bias_exp       = (float*)alloc((size_t)NHEAD * 36 * 37 * 4);

    const int MB = (NROWS + 127) / 128;        // 289 M-tiles

    // 1. prep: weight transposes || bias/rel-bias pack || LN1 (one dispatch)
    prep_kernel<<<TPOSE_BLKS + SPACK_BLKS + LN1_BLKS, 256, 0, stream>>>(
        w_q, w_kv, w_fc1, w_fc2, Wqkv_t, Wfc1_t, Wfc2_t,
        b_q, b_kv, rel, bqkv, bias_exp,
        x, xavg, g1, be1, (unsigned short*)xn);
    // 2. QKV GEMM: [36880,512] x [512,1536] -> qkv bf16 (LDS epilogue)
    gemm_kernel<false, true, false, true><<<12 * MB, 256, 0, stream>>>(
        xn, (const short*)Wqkv_t, bqkv, qkv_h, nullptr, NROWS, 1536, 512, 12);
    // 3. MFMA windowed attention || global-token attention (+ residual) -> XALL
    attn_kernel<<<8192 + 256, 128, 0, stream>>>(qkv_h, bias_exp, x, xavg, XALL);
    // 4. LN2 -> xn (bf16)
    ln_kernel<<<(NROWS + 3) / 4, 256, 0, stream>>>(XALL, g2, be2, (unsigned short*)xn, NROWS);
    // 5. FC1 + GELU: [36880,512] x [512,2048] -> hidden bf16 (LDS epilogue)
    gemm_kernel<true, true, false, true><<<16 * MB, 256, 0, stream>>>(
        xn, (const short*)Wfc1_t, b_fc1, qkv_h, nullptr, NROWS, 2048, 512, 16);
    // 6. FC2 + bias + residual: [36880,2048] x [2048,512] -> d_out f32 (direct epilogue)
    gemm_kernel<false, false, true, false><<<4 * MB, 256, 0, stream>>>(
        qkv_h, (const short*)Wfc2_t, b_fc2, d_out, XALL, NROWS, 512, 2048, 4);
}

// Round 14
// 683.912 us; speedup vs baseline: 1.1015x; 1.1015x over previous
//
#include <hip/hip_runtime.h>
#include <stdint.h>

#define DIM 512
#define NHEAD 16
#define HEADD 32
#define BATCH 16
#define SEQL 2304
#define XROWS (BATCH*SEQL)        // 36864
#define NROWS (XROWS + BATCH)     // 36880
#define ATT_SCALE 0.17677669529663687f

typedef __attribute__((ext_vector_type(8))) short short8;
typedef __attribute__((ext_vector_type(4))) float f32x4;

__device__ __forceinline__ float bf2f(unsigned short v) {
    union { unsigned u; float f; } t; t.u = ((unsigned)v) << 16; return t.f;
}
__device__ __forceinline__ unsigned short f2bf(float f) {
    union { float f; unsigned u; } t; t.f = f;
    unsigned r = t.u + 0x7fffu + ((t.u >> 16) & 1u);
    return (unsigned short)(r >> 16);
}
__device__ __forceinline__ void unpack8(const int4 c, float* o) {
    union { unsigned u; float f; } t;
    unsigned w0 = (unsigned)c.x, w1 = (unsigned)c.y, w2 = (unsigned)c.z, w3 = (unsigned)c.w;
    t.u = w0 << 16;         o[0] = t.f;
    t.u = w0 & 0xffff0000u; o[1] = t.f;
    t.u = w1 << 16;         o[2] = t.f;
    t.u = w1 & 0xffff0000u; o[3] = t.f;
    t.u = w2 << 16;         o[4] = t.f;
    t.u = w2 & 0xffff0000u; o[5] = t.f;
    t.u = w3 << 16;         o[6] = t.f;
    t.u = w3 & 0xffff0000u; o[7] = t.f;
}
__device__ __forceinline__ void gl_lds16(const void* g, void* l) {
    __builtin_amdgcn_global_load_lds((const __attribute__((address_space(1))) unsigned int*)g,
                                     (__attribute__((address_space(3))) unsigned int*)l,
                                     16, 0, 0);
}

// Branch-free exact-precision GELU: erf via Abramowitz-Stegun 7.1.26 (|err| <= 1.5e-7).
__device__ __forceinline__ float gelu_exact(float v) {
    union { float f; unsigned u; } zc; zc.f = v * 0.70710678118654752f;  // z = v/sqrt(2)
    unsigned sgn = zc.u & 0x80000000u;
    union { float f; unsigned u; } az; az.u = zc.u & 0x7fffffffu;        // |z|
    float t  = __builtin_amdgcn_rcpf(fmaf(0.3275911f, az.f, 1.0f));
    float p  = t * fmaf(t, fmaf(t, fmaf(t, fmaf(t, 1.061405429f, -1.453152027f),
                                        1.421413741f), -0.284496736f), 0.254829592f);
    float e  = __expf(-az.f * az.f);
    union { float f; unsigned u; } er; er.f = fmaf(-p, e, 1.0f);         // erf(|z|)
    er.u |= sgn;                                                         // erf(z)
    return 0.5f * v * (1.0f + er.f);
}

// LayerNorm for one 512-elem row: one wave, bf16 output.
__device__ __forceinline__ void ln_row(const float* __restrict__ src, int lane,
                                       const float* __restrict__ g, const float* __restrict__ be,
                                       unsigned short* __restrict__ outrow) {
    int c0 = lane * 8;
    float4 v0 = *(const float4*)(src + c0);
    float4 v1 = *(const float4*)(src + c0 + 4);
    float s = v0.x+v0.y+v0.z+v0.w + v1.x+v1.y+v1.z+v1.w;
    float q = v0.x*v0.x+v0.y*v0.y+v0.z*v0.z+v0.w*v0.w + v1.x*v1.x+v1.y*v1.y+v1.z*v1.z+v1.w*v1.w;
    for (int m = 1; m < 64; m <<= 1) { s += __shfl_xor(s, m); q += __shfl_xor(q, m); }
    float mean = s * (1.0f/512.0f);
    float var  = q * (1.0f/512.0f) - mean*mean;
    float rs = rsqrtf(var + 1e-3f);
    float4 g0 = *(const float4*)(g + c0);
    float4 g1 = *(const float4*)(g + c0 + 4);
    float4 b0 = *(const float4*)(be + c0);
    float4 b1 = *(const float4*)(be + c0 + 4);
    unsigned short o[8];
    o[0] = f2bf((v0.x-mean)*rs*g0.x + b0.x);
    o[1] = f2bf((v0.y-mean)*rs*g0.y + b0.y);
    o[2] = f2bf((v0.z-mean)*rs*g0.z + b0.z);
    o[3] = f2bf((v0.w-mean)*rs*g0.w + b0.w);
    o[4] = f2bf((v1.x-mean)*rs*g1.x + b1.x);
    o[5] = f2bf((v1.y-mean)*rs*g1.y + b1.y);
    o[6] = f2bf((v1.z-mean)*rs*g1.z + b1.z);
    o[7] = f2bf((v1.w-mean)*rs*g1.w + b1.w);
    *(int4*)(outrow + c0) = *(const int4*)o;
}

// ---------------- prep: weight transposes || bias/rel-bias pack || LN1 -------------------
#define TPOSE_BLKS 2816
#define SPACK_BLKS 90
#define LN1_BLKS   9220
__global__ __launch_bounds__(256) void prep_kernel(const float* __restrict__ w_q,
                                                   const float* __restrict__ w_kv,
                                                   const float* __restrict__ w_fc1,
                                                   const float* __restrict__ w_fc2,
                                                   unsigned short* __restrict__ Wqkv_t,
                                                   unsigned short* __restrict__ Wfc1_t,
                                                   unsigned short* __restrict__ Wfc2_t,
                                                   const float* __restrict__ b_q,
                                                   const float* __restrict__ b_kv,
                                                   const float* __restrict__ rel_table,
                                                   float* __restrict__ bqkv,
                                                   float* __restrict__ bias_exp,
                                                   const float* __restrict__ x,
                                                   const float* __restrict__ xavg,
                                                   const float* __restrict__ g1,
                                                   const float* __restrict__ be1,
                                                   unsigned short* __restrict__ xn) {
    __shared__ float tile[32][33];
    int blk = blockIdx.x;
    if (blk < TPOSE_BLKS) {
        int t = blk;
        const float* src; unsigned short* dst;
        int Kd, Nd, rowOff, tk;
        if (t < 256)        { src = w_q;   dst = Wqkv_t; Kd = 512;  Nd = 512;  rowOff = 0;   tk = 16; }
        else if (t < 768)   { t -= 256;  src = w_kv;  dst = Wqkv_t; Kd = 512;  Nd = 1024; rowOff = 512; tk = 16; }
        else if (t < 1792)  { t -= 768;  src = w_fc1; dst = Wfc1_t; Kd = 512;  Nd = 2048; rowOff = 0;   tk = 16; }
        else                { t -= 1792; src = w_fc2; dst = Wfc2_t; Kd = 2048; Nd = 512;  rowOff = 0;   tk = 64; }
        int k0 = (t % tk) * 32;
        int n0 = (t / tk) * 32;
        int tx = threadIdx.x & 31, ty = threadIdx.x >> 5;
        #pragma unroll
        for (int r = 0; r < 32; r += 8)
            tile[r + ty][tx] = src[(long)(k0 + r + ty) * Nd + n0 + tx];
        __syncthreads();
        #pragma unroll
        for (int r = 0; r < 32; r += 8)
            dst[(long)(rowOff + n0 + r + ty) * Kd + k0 + tx] = f2bf(tile[tx][r + ty]);
        return;
    }
    blk -= TPOSE_BLKS;
    if (blk < SPACK_BLKS) {
        int i = blk * 256 + threadIdx.x;
        if (i < 1536) { bqkv[i] = (i < 512) ? b_q[i] : b_kv[i - 512]; return; }
        i -= 1536;
        if (i < NHEAD*36*37) {                    // bias_exp[h][qi][j]
            int h = i / (36*37); int rem = i % (36*37); int qi = rem / 37; int j = rem % 37;
            int c0m = qi % 6, c1m = qi / 6;
            int c0n = (j < 36) ? (j % 6) : 0;
            int c1n = (j < 36) ? (j / 6) : 0;
            int id = (c0m - c0n + 5) * 11 + (c1m - c1n + 5);
            bias_exp[i] = rel_table[id * NHEAD + h];
        }
        return;
    }
    blk -= SPACK_BLKS;
    int wv = threadIdx.x >> 6, lane = threadIdx.x & 63;
    int r = blk * 4 + wv;
    if (r >= NROWS) return;
    const float* src = (r < XROWS) ? (x + (long)r * DIM) : (xavg + (long)(r - XROWS) * DIM);
    ln_row(src, lane, g1, be1, xn + (long)r * DIM);
}

// ---------------- LN2: one wave per row -------------------------------------------------
__global__ __launch_bounds__(256) void ln_kernel(const float* __restrict__ p1,
                                                 const float* __restrict__ g, const float* __restrict__ be,
                                                 unsigned short* __restrict__ out, int nrows) {
    int wv = threadIdx.x >> 6, lane = threadIdx.x & 63;
    int r = blockIdx.x * 4 + wv;
    if (r >= nrows) return;
    ln_row(p1 + (long)r * DIM, lane, g, be, out + (long)r * DIM);
}

// ---------------- bf16 MFMA GEMM: round-2 K-loop; epilogue templated per output ---------
// 128x128 tile, BK=64, single-buffered 32 KB LDS, two __syncthreads per K-step.
// K-loop CLOSED (rounds 3-9 ablation). Epilogue (round 10-11 A/B): LDS-coalesced path
// pays for bf16 scatter stores (QKV/FC1), hurts f32 path (FC2) -> LDS_EPI flag.
template<bool GELU_ACT, bool OUT_BF16, bool HAS_RES, bool LDS_EPI>
__global__ __launch_bounds__(256) void gemm_kernel(const short* __restrict__ A,
                                                   const short* __restrict__ Bt,
                                                   const float* __restrict__ bias,
                                                   void* __restrict__ Cout,
                                                   const float* __restrict__ Res,
                                                   int M, int N, int K, int nbx) {
    __shared__ short lds[2 * 128 * 64];        // 32 KB: a | b during K-loop; C-tile after
    short* lds_a = lds;
    short* lds_b = lds + 128 * 64;
    const int tid = threadIdx.x;
    const int lane = tid & 63;
    const int wv = tid >> 6;

    const int nwg = gridDim.x;
    const int orig = blockIdx.x;
    const int q = nwg >> 3, r = nwg & 7;
    const int xcd = orig & 7, lid = orig >> 3;
    const int wg = (xcd < r ? xcd * (q + 1) : r * (q + 1) + (xcd - r) * q) + lid;
    const int m0 = (wg / nbx) * 128;
    const int n0 = (wg % nbx) * 128;
    const int wm = (wv >> 1) * 64;
    const int wn = (wv & 1) * 64;

    f32x4 acc[4][4];
    #pragma unroll
    for (int i = 0; i < 4; i++)
        #pragma unroll
        for (int j = 0; j < 4; j++) { acc[i][j][0]=0.f; acc[i][j][1]=0.f; acc[i][j][2]=0.f; acc[i][j][3]=0.f; }

    const int srow = tid >> 3;                 // 0..31
    const int msl  = (tid & 7) ^ (srow & 7);
    const short* Aa = A + (long)(m0 + srow) * K + msl * 8;
    const short* Bb = Bt + (long)(n0 + srow) * K + msl * 8;
    short* la = lds_a + tid * 8;
    short* lb = lds_b + tid * 8;

    const int quad = lane >> 4;
    const int l15 = lane & 15;
    const short* ra0 = lds_a + (wm + l15) * 64 + ((quad)     ^ (l15 & 7)) * 8;
    const short* ra1 = lds_a + (wm + l15) * 64 + ((4 + quad) ^ (l15 & 7)) * 8;
    const short* rb0 = lds_b + (wn + l15) * 64 + ((quad)     ^ (l15 & 7)) * 8;
    const short* rb1 = lds_b + (wn + l15) * 64 + ((4 + quad) ^ (l15 & 7)) * 8;

    for (int k0 = 0; k0 < K; k0 += 64) {
        __syncthreads();
        #pragma unroll
        for (int i = 0; i < 4; i++) {
            gl_lds16(Aa + (long)(i * 32) * K + k0, la + i * 256 * 8);
            gl_lds16(Bb + (long)(i * 32) * K + k0, lb + i * 256 * 8);
        }
        __syncthreads();
        short8 af[4], bf4[4];
        #pragma unroll
        for (int mt = 0; mt < 4; mt++) af[mt] = *(const short8*)(ra0 + mt * 16 * 64);
        #pragma unroll
        for (int nt = 0; nt < 4; nt++) bf4[nt] = *(const short8*)(rb0 + nt * 16 * 64);
        #pragma unroll
        for (int mt = 0; mt < 4; mt++)
            #pragma unroll
            for (int nt = 0; nt < 4; nt++)
                acc[mt][nt] = __builtin_amdgcn_mfma_f32_16x16x32_bf16(af[mt], bf4[nt], acc[mt][nt], 0, 0, 0);
        #pragma unroll
        for (int mt = 0; mt < 4; mt++) af[mt] = *(const short8*)(ra1 + mt * 16 * 64);
        #pragma unroll
        for (int nt = 0; nt < 4; nt++) bf4[nt] = *(const short8*)(rb1 + nt * 16 * 64);
        #pragma unroll
        for (int mt = 0; mt < 4; mt++)
            #pragma unroll
            for (int nt = 0; nt < 4; nt++)
                acc[mt][nt] = __builtin_amdgcn_mfma_f32_16x16x32_bf16(af[mt], bf4[nt], acc[mt][nt], 0, 0, 0);
    }

    if (LDS_EPI) {
        // LDS-coalesced C write (pays for bf16 scatter outputs)
        float* ctile = (float*)lds;                 // 32 rows x stride 132 f32
        const int lrow_w = ((wv >> 1) << 4) + quad * 4;
        const int col_w  = ((wv & 1) << 6) + l15;
        const int lrow_r = tid >> 3;
        const int cg     = tid & 7;
        const int sub    = lrow_r & 15, half = lrow_r >> 4;
        float bv[16];
        #pragma unroll
        for (int i = 0; i < 4; i++)
            *(float4*)(bv + i * 4) = *(const float4*)(bias + n0 + cg * 16 + i * 4);

        #pragma unroll
        for (int mt = 0; mt < 4; mt++) {
            __syncthreads();
            #pragma unroll
            for (int nt = 0; nt < 4; nt++)
                #pragma unroll
                for (int r2 = 0; r2 < 4; r2++)
                    ctile[(lrow_w + r2) * 132 + col_w + nt * 16] = acc[mt][nt][r2];
            __syncthreads();
            int grow = m0 + half * 64 + mt * 16 + sub;
            if (grow < M) {
                int gcol = n0 + cg * 16;
                float v[16];
                #pragma unroll
                for (int i = 0; i < 4; i++)
                    *(float4*)(v + i * 4) = *(const float4*)(ctile + lrow_r * 132 + cg * 16 + i * 4);
                float rv[16];
                if (HAS_RES) {
                    #pragma unroll
                    for (int i = 0; i < 4; i++)
                        *(float4*)(rv + i * 4) = *(const float4*)(Res + (long)grow * N + gcol + i * 4);
                }
                if (OUT_BF16) {
                    unsigned short ob[16];
                    #pragma unroll
                    for (int i = 0; i < 16; i++) {
                        float vv = v[i] + bv[i];
                        if (GELU_ACT) vv = gelu_exact(vv);
                        if (HAS_RES) vv += rv[i];
                        ob[i] = f2bf(vv);
                    }
                    unsigned short* dst = (unsigned short*)Cout + (long)grow * N + gcol;
                    *(int4*)dst       = *(const int4*)ob;
                    *(int4*)(dst + 8) = *(const int4*)(ob + 8);
                } else {
                    float* dst = (float*)Cout + (long)grow * N + gcol;
                    #pragma unroll
                    for (int i = 0; i < 4; i++) {
                        float4 ov;
                        float* vp = v + i * 4;
                        float* rp = rv + i * 4;
                        ov.x = vp[0] + bv[i*4+0]; ov.y = vp[1] + bv[i*4+1];
                        ov.z = vp[2] + bv[i*4+2]; ov.w = vp[3] + bv[i*4+3];
                        if (GELU_ACT) { ov.x = gelu_exact(ov.x); ov.y = gelu_exact(ov.y);
                                        ov.z = gelu_exact(ov.z); ov.w = gelu_exact(ov.w); }
                        if (HAS_RES) { ov.x += rp[0]; ov.y += rp[1]; ov.z += rp[2]; ov.w += rp[3]; }
                        *(float4*)(dst + i * 4) = ov;
                    }
                }
            }
        }
    } else {
        // direct fragment-order epilogue (best for f32 outputs — round 8/10 measured)
        #pragma unroll
        for (int mt = 0; mt < 4; mt++) {
            int rbase = m0 + wm + mt * 16 + quad * 4;
            #pragma unroll
            for (int nt = 0; nt < 4; nt++) {
                int col = n0 + wn + nt * 16 + l15;
                float bv = bias[col];
                #pragma unroll
                for (int r2 = 0; r2 < 4; r2++) {
                    int row = rbase + r2;
                    if (row < M) {
                        float v = acc[mt][nt][r2] + bv;
                        if (GELU_ACT) v = gelu_exact(v);
                        if (HAS_RES) v += Res[(long)row * N + col];
                        if (OUT_BF16) ((unsigned short*)Cout)[(long)row * N + col] = f2bf(v);
                        else          ((float*)Cout)[(long)row * N + col] = v;
                    }
                }
            }
        }
    }
}

// ---------------- attention: MFMA windowed (blocks 0..4095) || global-token (4096+) -----
// Round-11 structure (4 waves/block, 256 thr — proven best; round-12's 2-wave variant
// destroyed L2 locality, FETCH 209 MB, reverted). Single delta vs round 11: s_setprio(1)
// around MFMA clusters (m191: +4-7% for independent-wave attention blocks).
__global__ __launch_bounds__(256) void attn_kernel(const short* __restrict__ qkv,
                                                   const float* __restrict__ bias_exp,
                                                   const float* __restrict__ xin,
                                                   const float* __restrict__ xavg,
                                                   float* __restrict__ XALL) {
    __shared__ short vt[4][32 * 64];   // VT[d][j] bf16 (j padded to 64)
    __shared__ short pl[4][48 * 64];   // P[qi][j] bf16 (qi padded 48, j padded 64)
    __shared__ float sums[4][48];      // 1/rowsum per qi
    const int tid = threadIdx.x;
    if (blockIdx.x < 4096) {
        const int wv = tid >> 6;
        const int lane = tid & 63;
        const int gw = blockIdx.x * 4 + wv;            // global wave = (win, head)
        const int win = gw >> 4;
        const int h = gw & 15;
        const int b = win >> 6;
        const int i1 = (win >> 3) & 7;
        const int i3 = win & 7;
        short* VT = vt[wv];
        short* PL = pl[wv];
        float* SM = sums[wv];
        const int quad = lane >> 4;
        const int l15 = lane & 15;

        // zero-fill VT + PL pads
        {
            int4 z; z.x = 0; z.y = 0; z.z = 0; z.w = 0;
            int4* v4 = (int4*)VT;
            #pragma unroll
            for (int i = 0; i < 4; i++) v4[lane + 64 * i] = z;
            int4* p4 = (int4*)PL;
            #pragma unroll
            for (int i = 0; i < 6; i++) p4[lane + 64 * i] = z;
        }
        // stage V transposed, lane-per-column: lane j owns column j (conflict-free)
        if (lane < 37) {
            long grow;
            if (lane < 36) { int i2 = lane / 6, i4 = lane % 6; grow = (long)b * SEQL + (i1*6 + i2) * 48 + i3*6 + i4; }
            else grow = XROWS + b;
            const int4* vp = (const int4*)(qkv + grow * 1536 + 1024 + h * 32);
            int4 r0 = vp[0], r1 = vp[1], r2v = vp[2], r3 = vp[3];
            const unsigned short* u0 = (const unsigned short*)&r0;
            const unsigned short* u1 = (const unsigned short*)&r1;
            const unsigned short* u2 = (const unsigned short*)&r2v;
            const unsigned short* u3 = (const unsigned short*)&r3;
            #pragma unroll
            for (int t = 0; t < 8; t++) VT[t * 64 + lane]        = (short)u0[t];
            #pragma unroll
            for (int t = 0; t < 8; t++) VT[(8 + t) * 64 + lane]  = (short)u1[t];
            #pragma unroll
            for (int t = 0; t < 8; t++) VT[(16 + t) * 64 + lane] = (short)u2[t];
            #pragma unroll
            for (int t = 0; t < 8; t++) VT[(24 + t) * 64 + lane] = (short)u3[t];
        }
        __syncthreads();

        // A-frags (Q rows) and B-frags (K rows) directly from global (L2-hot)
        short8 qf[3], kf[3];
        #pragma unroll
        for (int tm = 0; tm < 3; tm++) {
            int qi = tm * 16 + l15;
            if (qi < 36) {
                int i2 = qi / 6, i4 = qi % 6;
                long grow = (long)b * SEQL + (i1*6 + i2) * 48 + i3*6 + i4;
                qf[tm] = *(const short8*)(qkv + grow * 1536 + h * 32 + quad * 8);
            } else {
                #pragma unroll
                for (int i = 0; i < 8; i++) qf[tm][i] = 0;
            }
        }
        #pragma unroll
        for (int tn = 0; tn < 3; tn++) {
            int j = tn * 16 + l15;
            if (j <= 36) {
                long grow;
                if (j < 36) { int i2 = j / 6, i4 = j % 6; grow = (long)b * SEQL + (i1*6 + i2) * 48 + i3*6 + i4; }
                else grow = XROWS + b;
                kf[tn] = *(const short8*)(qkv + grow * 1536 + 512 + h * 32 + quad * 8);
            } else {
                #pragma unroll
                for (int i = 0; i < 8; i++) kf[tn][i] = 0;
            }
        }
        // S = Q·K^T : 9 MFMAs
        f32x4 s[3][3];
        __builtin_amdgcn_s_setprio(1);
        #pragma unroll
        for (int tm = 0; tm < 3; tm++)
            #pragma unroll
            for (int tn = 0; tn < 3; tn++) {
                f32x4 z; z[0]=0.f; z[1]=0.f; z[2]=0.f; z[3]=0.f;
                s[tm][tn] = __builtin_amdgcn_mfma_f32_16x16x32_bf16(qf[tm], kf[tn], z, 0, 0, 0);
            }
        __builtin_amdgcn_s_setprio(0);
        // scale + bias + pad mask
        #pragma unroll
        for (int tm = 0; tm < 3; tm++)
            #pragma unroll
            for (int r = 0; r < 4; r++) {
                int qi = tm * 16 + quad * 4 + r;
                const float* bh = bias_exp + h * (36*37) + (qi < 36 ? qi : 35) * 37;
                #pragma unroll
                for (int tn = 0; tn < 3; tn++) {
                    int j = tn * 16 + l15;
                    float bv = bh[j <= 36 ? j : 36];
                    float v = fmaf(s[tm][tn][r], ATT_SCALE, bv);
                    s[tm][tn][r] = (j <= 36) ? v : -1e30f;
                }
            }
        // row softmax (rows live across the 16-lane l15 group + 3 in-lane tiles)
        #pragma unroll
        for (int tm = 0; tm < 3; tm++)
            #pragma unroll
            for (int r = 0; r < 4; r++) {
                float mx = fmaxf(fmaxf(s[tm][0][r], s[tm][1][r]), s[tm][2][r]);
                for (int m = 1; m < 16; m <<= 1) mx = fmaxf(mx, __shfl_xor(mx, m));
                float e0 = __expf(s[tm][0][r] - mx);
                float e1 = __expf(s[tm][1][r] - mx);
                float e2 = __expf(s[tm][2][r] - mx);
                float sum = e0 + e1 + e2;
                for (int m = 1; m < 16; m <<= 1) sum += __shfl_xor(sum, m);
                s[tm][0][r] = e0; s[tm][1][r] = e1; s[tm][2][r] = e2;
                if (l15 == 0) SM[tm * 16 + quad * 4 + r] = 1.0f / sum;
            }
        // P -> LDS (bf16), row-major [qi][j]
        #pragma unroll
        for (int tm = 0; tm < 3; tm++)
            #pragma unroll
            for (int r = 0; r < 4; r++) {
                int row = (tm * 16 + quad * 4 + r) * 64;
                #pragma unroll
                for (int tn = 0; tn < 3; tn++)
                    PL[row + tn * 16 + l15] = (short)f2bf(s[tm][tn][r]);
            }
        // PV: O^T(32x48) = VT(32x64) · P^T(64x48) : 12 MFMAs over 2 K-chunks
        f32x4 o[2][3];
        #pragma unroll
        for (int i = 0; i < 2; i++)
            #pragma unroll
            for (int j = 0; j < 3; j++) { o[i][j][0]=0.f; o[i][j][1]=0.f; o[i][j][2]=0.f; o[i][j][3]=0.f; }
        #pragma unroll
        for (int ch = 0; ch < 2; ch++) {
            short8 va[2], pb[3];
            #pragma unroll
            for (int tmd = 0; tmd < 2; tmd++)
                va[tmd] = *(const short8*)(VT + (tmd * 16 + l15) * 64 + ch * 32 + quad * 8);
            #pragma unroll
            for (int tnq = 0; tnq < 3; tnq++)
                pb[tnq] = *(const short8*)(PL + (tnq * 16 + l15) * 64 + ch * 32 + quad * 8);
            __builtin_amdgcn_s_setprio(1);
            #pragma unroll
            for (int tmd = 0; tmd < 2; tmd++)
                #pragma unroll
                for (int tnq = 0; tnq < 3; tnq++)
                    o[tmd][tnq] = __builtin_amdgcn_mfma_f32_16x16x32_bf16(va[tmd], pb[tnq], o[tmd][tnq], 0, 0, 0);
            __builtin_amdgcn_s_setprio(0);
        }
        // epilogue: lane holds col qi = tnq*16+l15, rows d = tmd*16+quad*4+r
        #pragma unroll
        for (int tnq = 0; tnq < 3; tnq++) {
            int qi = tnq * 16 + l15;
            if (qi >= 36) continue;
            int i2 = qi / 6, i4 = qi % 6;
            long growq = (long)b * SEQL + (i1*6 + i2) * 48 + i3*6 + i4;
            float is = SM[qi];
            #pragma unroll
            for (int tmd = 0; tmd < 2; tmd++) {
                long base = growq * DIM + h * 32 + tmd * 16 + quad * 4;
                float4 xv = *(const float4*)(xin + base);
                float4 ov;
                ov.x = xv.x + o[tmd][tnq][0] * is;
                ov.y = xv.y + o[tmd][tnq][1] * is;
                ov.z = xv.z + o[tmd][tnq][2] * is;
                ov.w = xv.w + o[tmd][tnq][3] * is;
                *(float4*)(XALL + base) = ov;
            }
        }
        return;
    }
    // ---- global-token attention: 1 block per (batch, head) ----
    {
        const int bb = blockIdx.x - 4096;
        const int b = bb >> 4;
        const int h = bb & 15;
        __shared__ float qs[32];
        __shared__ float redm[4], redsum[4];
        __shared__ float wout[4][32];
        if (tid < 32) qs[tid] = bf2f(((const unsigned short*)qkv)[(long)(XROWS + b) * 1536 + h * 32 + tid]);
        __syncthreads();
        float qr[32];
        #pragma unroll
        for (int d = 0; d < 32; d++) qr[d] = qs[d];
        float s[9];
        float mx = -1e30f;
        #pragma unroll
        for (int i = 0; i < 9; i++) {
            int t = tid + i * 256;
            const int4* kp = (const int4*)(qkv + (long)(b * SEQL + t) * 1536 + 512 + h * 32);
            float kr[32];
            unpack8(kp[0], kr); unpack8(kp[1], kr + 8); unpack8(kp[2], kr + 16); unpack8(kp[3], kr + 24);
            float d0 = 0.f, d1 = 0.f, d2 = 0.f, d3 = 0.f;
            #pragma unroll
            for (int dd = 0; dd < 8; dd++) {
                d0 += qr[dd] * kr[dd]; d1 += qr[8+dd] * kr[8+dd];
                d2 += qr[16+dd] * kr[16+dd]; d3 += qr[24+dd] * kr[24+dd];
            }
            s[i] = (d0 + d1 + d2 + d3) * ATT_SCALE;
            mx = fmaxf(mx, s[i]);
        }
        for (int m = 1; m < 64; m <<= 1) mx = fmaxf(mx, __shfl_xor(mx, m));
        if ((tid & 63) == 0) redm[tid >> 6] = mx;
        __syncthreads();
        mx = fmaxf(fmaxf(redm[0], redm[1]), fmaxf(redm[2], redm[3]));
        float sum = 0.f;
        #pragma unroll
        for (int i = 0; i < 9; i++) { s[i] = __expf(s[i] - mx); sum += s[i]; }
        for (int m = 1; m < 64; m <<= 1) sum += __shfl_xor(sum, m);
        if ((tid & 63) == 0) redsum[tid >> 6] = sum;
        __syncthreads();
        sum = redsum[0] + redsum[1] + redsum[2] + redsum[3];
        float o[32];
        #pragma unroll
        for (int d = 0; d < 32; d++) o[d] = 0.f;
        #pragma unroll
        for (int i = 0; i < 9; i++) {
            int t = tid + i * 256;
            const int4* vp = (const int4*)(qkv + (long)(b * SEQL + t) * 1536 + 1024 + h * 32);
            float vr[32];
            unpack8(vp[0], vr); unpack8(vp[1], vr + 8); unpack8(vp[2], vr + 16); unpack8(vp[3], vr + 24);
            float p = s[i];
            #pragma unroll
            for (int d = 0; d < 32; d++) o[d] += p * vr[d];
        }
        for (int m = 1; m < 64; m <<= 1) {
            #pragma unroll
            for (int d = 0; d < 32; d++) o[d] += __shfl_xor(o[d], m);
        }
        if ((tid & 63) == 0) {
            #pragma unroll
            for (int d = 0; d < 32; d++) wout[tid >> 6][d] = o[d];
        }
        __syncthreads();
        if (tid < 32) {
            float t = wout[0][tid] + wout[1][tid] + wout[2][tid] + wout[3][tid];
            XALL[(long)(XROWS + b) * DIM + h * 32 + tid] = xavg[b * DIM + h * 32 + tid] + t / sum;
        }
    }
}

// ---------------- launch --------------------------------------------------------------
extern "C" void kernel_launch(void* const* d_in, const int* in_sizes, int n_in,
                              void* d_out, int out_size, void* d_ws, size_t ws_size,
                              hipStream_t stream) {
    const float* x      = (const float*)d_in[0];
    const float* xavg   = (const float*)d_in[1];
    const float* w_kv   = (const float*)d_in[2];
    const float* b_kv   = (const float*)d_in[3];
    const float* w_q    = (const float*)d_in[4];
    const float* b_q    = (const float*)d_in[5];
    const float* rel    = (const float*)d_in[6];
    const float* g1     = (const float*)d_in[7];
    const float* be1    = (const float*)d_in[8];
    const float* g2     = (const float*)d_in[9];
    const float* be2    = (const float*)d_in[10];
    const float* w_fc1  = (const float*)d_in[11];
    const float* b_fc1  = (const float*)d_in[12];
    const float* w_fc2  = (const float*)d_in[13];
    const float* b_fc2  = (const float*)d_in[14];

    char* ws = (char*)d_ws;
    size_t off = 0;
    auto alloc = [&](size_t bytes) { void* p = ws + off; off += (bytes + 255) & ~(size_t)255; return p; };
    short* qkv_h          = (short*)alloc((size_t)NROWS * 2048 * 2);   // qkv (1536 cols), then MLP hidden (2048 cols)
    float* XALL           = (float*)alloc((size_t)NROWS * 512 * 4);    // attn + residual, f32
    short* xn             = (short*)alloc((size_t)NROWS * 512 * 2);    // LN output, bf16 (reused LN1/LN2)
    unsigned short* Wqkv_t = (unsigned short*)alloc((size_t)1536 * 512 * 2);
    unsigned short* Wfc1_t = (unsigned short*)alloc((size_t)2048 * 512 * 2);
    unsigned short* Wfc2_t = (unsigned short*)alloc((size_t)512 * 2048 * 2);
    float* bqkv           = (float*)alloc(1536 * 4);
    float* bias_exp       = (float*)alloc((size_t)NHEAD * 36 * 37 * 4);

    const int MB = (NROWS + 127) / 128;        // 289 M-tiles

    // 1. prep: weight transposes || bias/rel-bias pack || LN1 (one dispatch)
    prep_kernel<<<TPOSE_BLKS + SPACK_BLKS + LN1_BLKS, 256, 0, stream>>>(
        w_q, w_kv, w_fc1, w_fc2, Wqkv_t, Wfc1_t, Wfc2_t,
        b_q, b_kv, rel, bqkv, bias_exp,
        x, xavg, g1, be1, (unsigned short*)xn);
    // 2. QKV GEMM: [36880,512] x [512,1536] -> qkv bf16 (LDS epilogue)
    gemm_kernel<false, true, false, true><<<12 * MB, 256, 0, stream>>>(
        xn, (const short*)Wqkv_t, bqkv, qkv_h, nullptr, NROWS, 1536, 512, 12);
    // 3. MFMA windowed attention || global-token attention (+ residual) -> XALL
    attn_kernel<<<4096 + 256, 256, 0, stream>>>(qkv_h, bias_exp, x, xavg, XALL);
    // 4. LN2 -> xn (bf16)
    ln_kernel<<<(NROWS + 3) / 4, 256, 0, stream>>>(XALL, g2, be2, (unsigned short*)xn, NROWS);
    // 5. FC1 + GELU: [36880,512] x [512,2048] -> hidden bf16 (LDS epilogue)
    gemm_kernel<true, true, false, true><<<16 * MB, 256, 0, stream>>>(
        xn, (const short*)Wfc1_t, b_fc1, qkv_h, nullptr, NROWS, 2048, 512, 16);
    // 6. FC2 + bias + residual: [36880,2048] x [2048,512] -> d_out f32 (direct epilogue)
    gemm_kernel<false, false, true, false><<<4 * MB, 256, 0, stream>>>(
        qkv_h, (const short*)Wfc2_t, b_fc2, d_out, XALL, NROWS, 512, 2048, 4);
}

// Round 15
// 674.991 us; speedup vs baseline: 1.1160x; 1.0132x over previous
//
#include <hip/hip_runtime.h>
#include <stdint.h>

#define DIM 512
#define NHEAD 16
#define HEADD 32
#define BATCH 16
#define SEQL 2304
#define XROWS (BATCH*SEQL)        // 36864
#define NROWS (XROWS + BATCH)     // 36880
#define ATT_SCALE 0.17677669529663687f

typedef __attribute__((ext_vector_type(8))) short short8;
typedef __attribute__((ext_vector_type(4))) float f32x4;

__device__ __forceinline__ float bf2f(unsigned short v) {
    union { unsigned u; float f; } t; t.u = ((unsigned)v) << 16; return t.f;
}
__device__ __forceinline__ unsigned short f2bf(float f) {
    union { float f; unsigned u; } t; t.f = f;
    unsigned r = t.u + 0x7fffu + ((t.u >> 16) & 1u);
    return (unsigned short)(r >> 16);
}
__device__ __forceinline__ void unpack8(const int4 c, float* o) {
    union { unsigned u; float f; } t;
    unsigned w0 = (unsigned)c.x, w1 = (unsigned)c.y, w2 = (unsigned)c.z, w3 = (unsigned)c.w;
    t.u = w0 << 16;         o[0] = t.f;
    t.u = w0 & 0xffff0000u; o[1] = t.f;
    t.u = w1 << 16;         o[2] = t.f;
    t.u = w1 & 0xffff0000u; o[3] = t.f;
    t.u = w2 << 16;         o[4] = t.f;
    t.u = w2 & 0xffff0000u; o[5] = t.f;
    t.u = w3 << 16;         o[6] = t.f;
    t.u = w3 & 0xffff0000u; o[7] = t.f;
}
__device__ __forceinline__ void gl_lds16(const void* g, void* l) {
    __builtin_amdgcn_global_load_lds((const __attribute__((address_space(1))) unsigned int*)g,
                                     (__attribute__((address_space(3))) unsigned int*)l,
                                     16, 0, 0);
}

// Branch-free exact-precision GELU: erf via Abramowitz-Stegun 7.1.26 (|err| <= 1.5e-7).
__device__ __forceinline__ float gelu_exact(float v) {
    union { float f; unsigned u; } zc; zc.f = v * 0.70710678118654752f;  // z = v/sqrt(2)
    unsigned sgn = zc.u & 0x80000000u;
    union { float f; unsigned u; } az; az.u = zc.u & 0x7fffffffu;        // |z|
    float t  = __builtin_amdgcn_rcpf(fmaf(0.3275911f, az.f, 1.0f));
    float p  = t * fmaf(t, fmaf(t, fmaf(t, fmaf(t, 1.061405429f, -1.453152027f),
                                        1.421413741f), -0.284496736f), 0.254829592f);
    float e  = __expf(-az.f * az.f);
    union { float f; unsigned u; } er; er.f = fmaf(-p, e, 1.0f);         // erf(|z|)
    er.u |= sgn;                                                         // erf(z)
    return 0.5f * v * (1.0f + er.f);
}

// LayerNorm for one 512-elem row: one wave, bf16 output.
__device__ __forceinline__ void ln_row(const float* __restrict__ src, int lane,
                                       const float* __restrict__ g, const float* __restrict__ be,
                                       unsigned short* __restrict__ outrow) {
    int c0 = lane * 8;
    float4 v0 = *(const float4*)(src + c0);
    float4 v1 = *(const float4*)(src + c0 + 4);
    float s = v0.x+v0.y+v0.z+v0.w + v1.x+v1.y+v1.z+v1.w;
    float q = v0.x*v0.x+v0.y*v0.y+v0.z*v0.z+v0.w*v0.w + v1.x*v1.x+v1.y*v1.y+v1.z*v1.z+v1.w*v1.w;
    for (int m = 1; m < 64; m <<= 1) { s += __shfl_xor(s, m); q += __shfl_xor(q, m); }
    float mean = s * (1.0f/512.0f);
    float var  = q * (1.0f/512.0f) - mean*mean;
    float rs = rsqrtf(var + 1e-3f);
    float4 g0 = *(const float4*)(g + c0);
    float4 g1 = *(const float4*)(g + c0 + 4);
    float4 b0 = *(const float4*)(be + c0);
    float4 b1 = *(const float4*)(be + c0 + 4);
    unsigned short o[8];
    o[0] = f2bf((v0.x-mean)*rs*g0.x + b0.x);
    o[1] = f2bf((v0.y-mean)*rs*g0.y + b0.y);
    o[2] = f2bf((v0.z-mean)*rs*g0.z + b0.z);
    o[3] = f2bf((v0.w-mean)*rs*g0.w + b0.w);
    o[4] = f2bf((v1.x-mean)*rs*g1.x + b1.x);
    o[5] = f2bf((v1.y-mean)*rs*g1.y + b1.y);
    o[6] = f2bf((v1.z-mean)*rs*g1.z + b1.z);
    o[7] = f2bf((v1.w-mean)*rs*g1.w + b1.w);
    *(int4*)(outrow + c0) = *(const int4*)o;
}

// ---------------- prep: weight transposes || bias/rel-bias pack || LN1 -------------------
#define TPOSE_BLKS 2816
#define SPACK_BLKS 90
#define LN1_BLKS   9220
__global__ __launch_bounds__(256) void prep_kernel(const float* __restrict__ w_q,
                                                   const float* __restrict__ w_kv,
                                                   const float* __restrict__ w_fc1,
                                                   const float* __restrict__ w_fc2,
                                                   unsigned short* __restrict__ Wqkv_t,
                                                   unsigned short* __restrict__ Wfc1_t,
                                                   unsigned short* __restrict__ Wfc2_t,
                                                   const float* __restrict__ b_q,
                                                   const float* __restrict__ b_kv,
                                                   const float* __restrict__ rel_table,
                                                   float* __restrict__ bqkv,
                                                   float* __restrict__ bias_exp,
                                                   const float* __restrict__ x,
                                                   const float* __restrict__ xavg,
                                                   const float* __restrict__ g1,
                                                   const float* __restrict__ be1,
                                                   unsigned short* __restrict__ xn) {
    __shared__ float tile[32][33];
    int blk = blockIdx.x;
    if (blk < TPOSE_BLKS) {
        int t = blk;
        const float* src; unsigned short* dst;
        int Kd, Nd, rowOff, tk;
        if (t < 256)        { src = w_q;   dst = Wqkv_t; Kd = 512;  Nd = 512;  rowOff = 0;   tk = 16; }
        else if (t < 768)   { t -= 256;  src = w_kv;  dst = Wqkv_t; Kd = 512;  Nd = 1024; rowOff = 512; tk = 16; }
        else if (t < 1792)  { t -= 768;  src = w_fc1; dst = Wfc1_t; Kd = 512;  Nd = 2048; rowOff = 0;   tk = 16; }
        else                { t -= 1792; src = w_fc2; dst = Wfc2_t; Kd = 2048; Nd = 512;  rowOff = 0;   tk = 64; }
        int k0 = (t % tk) * 32;
        int n0 = (t / tk) * 32;
        int tx = threadIdx.x & 31, ty = threadIdx.x >> 5;
        #pragma unroll
        for (int r = 0; r < 32; r += 8)
            tile[r + ty][tx] = src[(long)(k0 + r + ty) * Nd + n0 + tx];
        __syncthreads();
        #pragma unroll
        for (int r = 0; r < 32; r += 8)
            dst[(long)(rowOff + n0 + r + ty) * Kd + k0 + tx] = f2bf(tile[tx][r + ty]);
        return;
    }
    blk -= TPOSE_BLKS;
    if (blk < SPACK_BLKS) {
        int i = blk * 256 + threadIdx.x;
        if (i < 1536) { bqkv[i] = (i < 512) ? b_q[i] : b_kv[i - 512]; return; }
        i -= 1536;
        if (i < NHEAD*36*37) {                    // bias_exp[h][qi][j]
            int h = i / (36*37); int rem = i % (36*37); int qi = rem / 37; int j = rem % 37;
            int c0m = qi % 6, c1m = qi / 6;
            int c0n = (j < 36) ? (j % 6) : 0;
            int c1n = (j < 36) ? (j / 6) : 0;
            int id = (c0m - c0n + 5) * 11 + (c1m - c1n + 5);
            bias_exp[i] = rel_table[id * NHEAD + h];
        }
        return;
    }
    blk -= SPACK_BLKS;
    int wv = threadIdx.x >> 6, lane = threadIdx.x & 63;
    int r = blk * 4 + wv;
    if (r >= NROWS) return;
    const float* src = (r < XROWS) ? (x + (long)r * DIM) : (xavg + (long)(r - XROWS) * DIM);
    ln_row(src, lane, g1, be1, xn + (long)r * DIM);
}

// ---------------- LN2: one wave per row -------------------------------------------------
__global__ __launch_bounds__(256) void ln_kernel(const float* __restrict__ p1,
                                                 const float* __restrict__ g, const float* __restrict__ be,
                                                 unsigned short* __restrict__ out, int nrows) {
    int wv = threadIdx.x >> 6, lane = threadIdx.x & 63;
    int r = blockIdx.x * 4 + wv;
    if (r >= nrows) return;
    ln_row(p1 + (long)r * DIM, lane, g, be, out + (long)r * DIM);
}

// ---------------- bf16 MFMA GEMM: round-2 K-loop; epilogue templated per output ---------
// 128x128 tile, BK=64, single-buffered 32 KB LDS, two __syncthreads per K-step.
// K-loop CLOSED (rounds 3-9 ablation). Epilogue (round 10-11 A/B): LDS-coalesced path
// pays for bf16 scatter stores (QKV/FC1), hurts f32 path (FC2) -> LDS_EPI flag.
template<bool GELU_ACT, bool OUT_BF16, bool HAS_RES, bool LDS_EPI>
__global__ __launch_bounds__(256) void gemm_kernel(const short* __restrict__ A,
                                                   const short* __restrict__ Bt,
                                                   const float* __restrict__ bias,
                                                   void* __restrict__ Cout,
                                                   const float* __restrict__ Res,
                                                   int M, int N, int K, int nbx) {
    __shared__ short lds[2 * 128 * 64];        // 32 KB: a | b during K-loop; C-tile after
    short* lds_a = lds;
    short* lds_b = lds + 128 * 64;
    const int tid = threadIdx.x;
    const int lane = tid & 63;
    const int wv = tid >> 6;

    const int nwg = gridDim.x;
    const int orig = blockIdx.x;
    const int q = nwg >> 3, r = nwg & 7;
    const int xcd = orig & 7, lid = orig >> 3;
    const int wg = (xcd < r ? xcd * (q + 1) : r * (q + 1) + (xcd - r) * q) + lid;
    const int m0 = (wg / nbx) * 128;
    const int n0 = (wg % nbx) * 128;
    const int wm = (wv >> 1) * 64;
    const int wn = (wv & 1) * 64;

    f32x4 acc[4][4];
    #pragma unroll
    for (int i = 0; i < 4; i++)
        #pragma unroll
        for (int j = 0; j < 4; j++) { acc[i][j][0]=0.f; acc[i][j][1]=0.f; acc[i][j][2]=0.f; acc[i][j][3]=0.f; }

    const int srow = tid >> 3;                 // 0..31
    const int msl  = (tid & 7) ^ (srow & 7);
    const short* Aa = A + (long)(m0 + srow) * K + msl * 8;
    const short* Bb = Bt + (long)(n0 + srow) * K + msl * 8;
    short* la = lds_a + tid * 8;
    short* lb = lds_b + tid * 8;

    const int quad = lane >> 4;
    const int l15 = lane & 15;
    const short* ra0 = lds_a + (wm + l15) * 64 + ((quad)     ^ (l15 & 7)) * 8;
    const short* ra1 = lds_a + (wm + l15) * 64 + ((4 + quad) ^ (l15 & 7)) * 8;
    const short* rb0 = lds_b + (wn + l15) * 64 + ((quad)     ^ (l15 & 7)) * 8;
    const short* rb1 = lds_b + (wn + l15) * 64 + ((4 + quad) ^ (l15 & 7)) * 8;

    for (int k0 = 0; k0 < K; k0 += 64) {
        __syncthreads();
        #pragma unroll
        for (int i = 0; i < 4; i++) {
            gl_lds16(Aa + (long)(i * 32) * K + k0, la + i * 256 * 8);
            gl_lds16(Bb + (long)(i * 32) * K + k0, lb + i * 256 * 8);
        }
        __syncthreads();
        short8 af[4], bf4[4];
        #pragma unroll
        for (int mt = 0; mt < 4; mt++) af[mt] = *(const short8*)(ra0 + mt * 16 * 64);
        #pragma unroll
        for (int nt = 0; nt < 4; nt++) bf4[nt] = *(const short8*)(rb0 + nt * 16 * 64);
        #pragma unroll
        for (int mt = 0; mt < 4; mt++)
            #pragma unroll
            for (int nt = 0; nt < 4; nt++)
                acc[mt][nt] = __builtin_amdgcn_mfma_f32_16x16x32_bf16(af[mt], bf4[nt], acc[mt][nt], 0, 0, 0);
        #pragma unroll
        for (int mt = 0; mt < 4; mt++) af[mt] = *(const short8*)(ra1 + mt * 16 * 64);
        #pragma unroll
        for (int nt = 0; nt < 4; nt++) bf4[nt] = *(const short8*)(rb1 + nt * 16 * 64);
        #pragma unroll
        for (int mt = 0; mt < 4; mt++)
            #pragma unroll
            for (int nt = 0; nt < 4; nt++)
                acc[mt][nt] = __builtin_amdgcn_mfma_f32_16x16x32_bf16(af[mt], bf4[nt], acc[mt][nt], 0, 0, 0);
    }

    if (LDS_EPI) {
        // LDS-coalesced C write (pays for bf16 scatter outputs)
        float* ctile = (float*)lds;                 // 32 rows x stride 132 f32
        const int lrow_w = ((wv >> 1) << 4) + quad * 4;
        const int col_w  = ((wv & 1) << 6) + l15;
        const int lrow_r = tid >> 3;
        const int cg     = tid & 7;
        const int sub    = lrow_r & 15, half = lrow_r >> 4;
        float bv[16];
        #pragma unroll
        for (int i = 0; i < 4; i++)
            *(float4*)(bv + i * 4) = *(const float4*)(bias + n0 + cg * 16 + i * 4);

        #pragma unroll
        for (int mt = 0; mt < 4; mt++) {
            __syncthreads();
            #pragma unroll
            for (int nt = 0; nt < 4; nt++)
                #pragma unroll
                for (int r2 = 0; r2 < 4; r2++)
                    ctile[(lrow_w + r2) * 132 + col_w + nt * 16] = acc[mt][nt][r2];
            __syncthreads();
            int grow = m0 + half * 64 + mt * 16 + sub;
            if (grow < M) {
                int gcol = n0 + cg * 16;
                float v[16];
                #pragma unroll
                for (int i = 0; i < 4; i++)
                    *(float4*)(v + i * 4) = *(const float4*)(ctile + lrow_r * 132 + cg * 16 + i * 4);
                float rv[16];
                if (HAS_RES) {
                    #pragma unroll
                    for (int i = 0; i < 4; i++)
                        *(float4*)(rv + i * 4) = *(const float4*)(Res + (long)grow * N + gcol + i * 4);
                }
                if (OUT_BF16) {
                    unsigned short ob[16];
                    #pragma unroll
                    for (int i = 0; i < 16; i++) {
                        float vv = v[i] + bv[i];
                        if (GELU_ACT) vv = gelu_exact(vv);
                        if (HAS_RES) vv += rv[i];
                        ob[i] = f2bf(vv);
                    }
                    unsigned short* dst = (unsigned short*)Cout + (long)grow * N + gcol;
                    *(int4*)dst       = *(const int4*)ob;
                    *(int4*)(dst + 8) = *(const int4*)(ob + 8);
                } else {
                    float* dst = (float*)Cout + (long)grow * N + gcol;
                    #pragma unroll
                    for (int i = 0; i < 4; i++) {
                        float4 ov;
                        float* vp = v + i * 4;
                        float* rp = rv + i * 4;
                        ov.x = vp[0] + bv[i*4+0]; ov.y = vp[1] + bv[i*4+1];
                        ov.z = vp[2] + bv[i*4+2]; ov.w = vp[3] + bv[i*4+3];
                        if (GELU_ACT) { ov.x = gelu_exact(ov.x); ov.y = gelu_exact(ov.y);
                                        ov.z = gelu_exact(ov.z); ov.w = gelu_exact(ov.w); }
                        if (HAS_RES) { ov.x += rp[0]; ov.y += rp[1]; ov.z += rp[2]; ov.w += rp[3]; }
                        *(float4*)(dst + i * 4) = ov;
                    }
                }
            }
        }
    } else {
        // direct fragment-order epilogue (best for f32 outputs — round 8/10 measured)
        #pragma unroll
        for (int mt = 0; mt < 4; mt++) {
            int rbase = m0 + wm + mt * 16 + quad * 4;
            #pragma unroll
            for (int nt = 0; nt < 4; nt++) {
                int col = n0 + wn + nt * 16 + l15;
                float bv = bias[col];
                #pragma unroll
                for (int r2 = 0; r2 < 4; r2++) {
                    int row = rbase + r2;
                    if (row < M) {
                        float v = acc[mt][nt][r2] + bv;
                        if (GELU_ACT) v = gelu_exact(v);
                        if (HAS_RES) v += Res[(long)row * N + col];
                        if (OUT_BF16) ((unsigned short*)Cout)[(long)row * N + col] = f2bf(v);
                        else          ((float*)Cout)[(long)row * N + col] = v;
                    }
                }
            }
        }
    }
}

// ---------------- attention: MFMA windowed (blocks 0..4095) || global-token (4096+) -----
// Final config = round-11 best (677 us): 4 waves/block, lane-per-column V staging,
// no setprio (round-14 A/B: null-to-negative; attn MfmaUtil ~1% -> nothing to arbitrate).
__global__ __launch_bounds__(256) void attn_kernel(const short* __restrict__ qkv,
                                                   const float* __restrict__ bias_exp,
                                                   const float* __restrict__ xin,
                                                   const float* __restrict__ xavg,
                                                   float* __restrict__ XALL) {
    __shared__ short vt[4][32 * 64];   // VT[d][j] bf16 (j padded to 64)
    __shared__ short pl[4][48 * 64];   // P[qi][j] bf16 (qi padded 48, j padded 64)
    __shared__ float sums[4][48];      // 1/rowsum per qi
    const int tid = threadIdx.x;
    if (blockIdx.x < 4096) {
        const int wv = tid >> 6;
        const int lane = tid & 63;
        const int gw = blockIdx.x * 4 + wv;            // global wave = (win, head)
        const int win = gw >> 4;
        const int h = gw & 15;
        const int b = win >> 6;
        const int i1 = (win >> 3) & 7;
        const int i3 = win & 7;
        short* VT = vt[wv];
        short* PL = pl[wv];
        float* SM = sums[wv];
        const int quad = lane >> 4;
        const int l15 = lane & 15;

        // zero-fill VT + PL pads
        {
            int4 z; z.x = 0; z.y = 0; z.z = 0; z.w = 0;
            int4* v4 = (int4*)VT;
            #pragma unroll
            for (int i = 0; i < 4; i++) v4[lane + 64 * i] = z;
            int4* p4 = (int4*)PL;
            #pragma unroll
            for (int i = 0; i < 6; i++) p4[lane + 64 * i] = z;
        }
        // stage V transposed, lane-per-column: lane j owns column j (conflict-free)
        if (lane < 37) {
            long grow;
            if (lane < 36) { int i2 = lane / 6, i4 = lane % 6; grow = (long)b * SEQL + (i1*6 + i2) * 48 + i3*6 + i4; }
            else grow = XROWS + b;
            const int4* vp = (const int4*)(qkv + grow * 1536 + 1024 + h * 32);
            int4 r0 = vp[0], r1 = vp[1], r2v = vp[2], r3 = vp[3];
            const unsigned short* u0 = (const unsigned short*)&r0;
            const unsigned short* u1 = (const unsigned short*)&r1;
            const unsigned short* u2 = (const unsigned short*)&r2v;
            const unsigned short* u3 = (const unsigned short*)&r3;
            #pragma unroll
            for (int t = 0; t < 8; t++) VT[t * 64 + lane]        = (short)u0[t];
            #pragma unroll
            for (int t = 0; t < 8; t++) VT[(8 + t) * 64 + lane]  = (short)u1[t];
            #pragma unroll
            for (int t = 0; t < 8; t++) VT[(16 + t) * 64 + lane] = (short)u2[t];
            #pragma unroll
            for (int t = 0; t < 8; t++) VT[(24 + t) * 64 + lane] = (short)u3[t];
        }
        __syncthreads();

        // A-frags (Q rows) and B-frags (K rows) directly from global (L2-hot)
        short8 qf[3], kf[3];
        #pragma unroll
        for (int tm = 0; tm < 3; tm++) {
            int qi = tm * 16 + l15;
            if (qi < 36) {
                int i2 = qi / 6, i4 = qi % 6;
                long grow = (long)b * SEQL + (i1*6 + i2) * 48 + i3*6 + i4;
                qf[tm] = *(const short8*)(qkv + grow * 1536 + h * 32 + quad * 8);
            } else {
                #pragma unroll
                for (int i = 0; i < 8; i++) qf[tm][i] = 0;
            }
        }
        #pragma unroll
        for (int tn = 0; tn < 3; tn++) {
            int j = tn * 16 + l15;
            if (j <= 36) {
                long grow;
                if (j < 36) { int i2 = j / 6, i4 = j % 6; grow = (long)b * SEQL + (i1*6 + i2) * 48 + i3*6 + i4; }
                else grow = XROWS + b;
                kf[tn] = *(const short8*)(qkv + grow * 1536 + 512 + h * 32 + quad * 8);
            } else {
                #pragma unroll
                for (int i = 0; i < 8; i++) kf[tn][i] = 0;
            }
        }
        // S = Q·K^T : 9 MFMAs
        f32x4 s[3][3];
        #pragma unroll
        for (int tm = 0; tm < 3; tm++)
            #pragma unroll
            for (int tn = 0; tn < 3; tn++) {
                f32x4 z; z[0]=0.f; z[1]=0.f; z[2]=0.f; z[3]=0.f;
                s[tm][tn] = __builtin_amdgcn_mfma_f32_16x16x32_bf16(qf[tm], kf[tn], z, 0, 0, 0);
            }
        // scale + bias + pad mask
        #pragma unroll
        for (int tm = 0; tm < 3; tm++)
            #pragma unroll
            for (int r = 0; r < 4; r++) {
                int qi = tm * 16 + quad * 4 + r;
                const float* bh = bias_exp + h * (36*37) + (qi < 36 ? qi : 35) * 37;
                #pragma unroll
                for (int tn = 0; tn < 3; tn++) {
                    int j = tn * 16 + l15;
                    float bv = bh[j <= 36 ? j : 36];
                    float v = fmaf(s[tm][tn][r], ATT_SCALE, bv);
                    s[tm][tn][r] = (j <= 36) ? v : -1e30f;
                }
            }
        // row softmax (rows live across the 16-lane l15 group + 3 in-lane tiles)
        #pragma unroll
        for (int tm = 0; tm < 3; tm++)
            #pragma unroll
            for (int r = 0; r < 4; r++) {
                float mx = fmaxf(fmaxf(s[tm][0][r], s[tm][1][r]), s[tm][2][r]);
                for (int m = 1; m < 16; m <<= 1) mx = fmaxf(mx, __shfl_xor(mx, m));
                float e0 = __expf(s[tm][0][r] - mx);
                float e1 = __expf(s[tm][1][r] - mx);
                float e2 = __expf(s[tm][2][r] - mx);
                float sum = e0 + e1 + e2;
                for (int m = 1; m < 16; m <<= 1) sum += __shfl_xor(sum, m);
                s[tm][0][r] = e0; s[tm][1][r] = e1; s[tm][2][r] = e2;
                if (l15 == 0) SM[tm * 16 + quad * 4 + r] = 1.0f / sum;
            }
        // P -> LDS (bf16), row-major [qi][j]
        #pragma unroll
        for (int tm = 0; tm < 3; tm++)
            #pragma unroll
            for (int r = 0; r < 4; r++) {
                int row = (tm * 16 + quad * 4 + r) * 64;
                #pragma unroll
                for (int tn = 0; tn < 3; tn++)
                    PL[row + tn * 16 + l15] = (short)f2bf(s[tm][tn][r]);
            }
        // PV: O^T(32x48) = VT(32x64) · P^T(64x48) : 12 MFMAs over 2 K-chunks
        f32x4 o[2][3];
        #pragma unroll
        for (int i = 0; i < 2; i++)
            #pragma unroll
            for (int j = 0; j < 3; j++) { o[i][j][0]=0.f; o[i][j][1]=0.f; o[i][j][2]=0.f; o[i][j][3]=0.f; }
        #pragma unroll
        for (int ch = 0; ch < 2; ch++) {
            short8 va[2], pb[3];
            #pragma unroll
            for (int tmd = 0; tmd < 2; tmd++)
                va[tmd] = *(const short8*)(VT + (tmd * 16 + l15) * 64 + ch * 32 + quad * 8);
            #pragma unroll
            for (int tnq = 0; tnq < 3; tnq++)
                pb[tnq] = *(const short8*)(PL + (tnq * 16 + l15) * 64 + ch * 32 + quad * 8);
            #pragma unroll
            for (int tmd = 0; tmd < 2; tmd++)
                #pragma unroll
                for (int tnq = 0; tnq < 3; tnq++)
                    o[tmd][tnq] = __builtin_amdgcn_mfma_f32_16x16x32_bf16(va[tmd], pb[tnq], o[tmd][tnq], 0, 0, 0);
        }
        // epilogue: lane holds col qi = tnq*16+l15, rows d = tmd*16+quad*4+r
        #pragma unroll
        for (int tnq = 0; tnq < 3; tnq++) {
            int qi = tnq * 16 + l15;
            if (qi >= 36) continue;
            int i2 = qi / 6, i4 = qi % 6;
            long growq = (long)b * SEQL + (i1*6 + i2) * 48 + i3*6 + i4;
            float is = SM[qi];
            #pragma unroll
            for (int tmd = 0; tmd < 2; tmd++) {
                long base = growq * DIM + h * 32 + tmd * 16 + quad * 4;
                float4 xv = *(const float4*)(xin + base);
                float4 ov;
                ov.x = xv.x + o[tmd][tnq][0] * is;
                ov.y = xv.y + o[tmd][tnq][1] * is;
                ov.z = xv.z + o[tmd][tnq][2] * is;
                ov.w = xv.w + o[tmd][tnq][3] * is;
                *(float4*)(XALL + base) = ov;
            }
        }
        return;
    }
    // ---- global-token attention: 1 block per (batch, head) ----
    {
        const int bb = blockIdx.x - 4096;
        const int b = bb >> 4;
        const int h = bb & 15;
        __shared__ float qs[32];
        __shared__ float redm[4], redsum[4];
        __shared__ float wout[4][32];
        if (tid < 32) qs[tid] = bf2f(((const unsigned short*)qkv)[(long)(XROWS + b) * 1536 + h * 32 + tid]);
        __syncthreads();
        float qr[32];
        #pragma unroll
        for (int d = 0; d < 32; d++) qr[d] = qs[d];
        float s[9];
        float mx = -1e30f;
        #pragma unroll
        for (int i = 0; i < 9; i++) {
            int t = tid + i * 256;
            const int4* kp = (const int4*)(qkv + (long)(b * SEQL + t) * 1536 + 512 + h * 32);
            float kr[32];
            unpack8(kp[0], kr); unpack8(kp[1], kr + 8); unpack8(kp[2], kr + 16); unpack8(kp[3], kr + 24);
            float d0 = 0.f, d1 = 0.f, d2 = 0.f, d3 = 0.f;
            #pragma unroll
            for (int dd = 0; dd < 8; dd++) {
                d0 += qr[dd] * kr[dd]; d1 += qr[8+dd] * kr[8+dd];
                d2 += qr[16+dd] * kr[16+dd]; d3 += qr[24+dd] * kr[24+dd];
            }
            s[i] = (d0 + d1 + d2 + d3) * ATT_SCALE;
            mx = fmaxf(mx, s[i]);
        }
        for (int m = 1; m < 64; m <<= 1) mx = fmaxf(mx, __shfl_xor(mx, m));
        if ((tid & 63) == 0) redm[tid >> 6] = mx;
        __syncthreads();
        mx = fmaxf(fmaxf(redm[0], redm[1]), fmaxf(redm[2], redm[3]));
        float sum = 0.f;
        #pragma unroll
        for (int i = 0; i < 9; i++) { s[i] = __expf(s[i] - mx); sum += s[i]; }
        for (int m = 1; m < 64; m <<= 1) sum += __shfl_xor(sum, m);
        if ((tid & 63) == 0) redsum[tid >> 6] = sum;
        __syncthreads();
        sum = redsum[0] + redsum[1] + redsum[2] + redsum[3];
        float o[32];
        #pragma unroll
        for (int d = 0; d < 32; d++) o[d] = 0.f;
        #pragma unroll
        for (int i = 0; i < 9; i++) {
            int t = tid + i * 256;
            const int4* vp = (const int4*)(qkv + (long)(b * SEQL + t) * 1536 + 1024 + h * 32);
            float vr[32];
            unpack8(vp[0], vr); unpack8(vp[1], vr + 8); unpack8(vp[2], vr + 16); unpack8(vp[3], vr + 24);
            float p = s[i];
            #pragma unroll
            for (int d = 0; d < 32; d++) o[d] += p * vr[d];
        }
        for (int m = 1; m < 64; m <<= 1) {
            #pragma unroll
            for (int d = 0; d < 32; d++) o[d] += __shfl_xor(o[d], m);
        }
        if ((tid & 63) == 0) {
            #pragma unroll
            for (int d = 0; d < 32; d++) wout[tid >> 6][d] = o[d];
        }
        __syncthreads();
        if (tid < 32) {
            float t = wout[0][tid] + wout[1][tid] + wout[2][tid] + wout[3][tid];
            XALL[(long)(XROWS + b) * DIM + h * 32 + tid] = xavg[b * DIM + h * 32 + tid] + t / sum;
        }
    }
}

// ---------------- launch --------------------------------------------------------------
extern "C" void kernel_launch(void* const* d_in, const int* in_sizes, int n_in,
                              void* d_out, int out_size, void* d_ws, size_t ws_size,
                              hipStream_t stream) {
    const float* x      = (const float*)d_in[0];
    const float* xavg   = (const float*)d_in[1];
    const float* w_kv   = (const float*)d_in[2];
    const float* b_kv   = (const float*)d_in[3];
    const float* w_q    = (const float*)d_in[4];
    const float* b_q    = (const float*)d_in[5];
    const float* rel    = (const float*)d_in[6];
    const float* g1     = (const float*)d_in[7];
    const float* be1    = (const float*)d_in[8];
    const float* g2     = (const float*)d_in[9];
    const float* be2    = (const float*)d_in[10];
    const float* w_fc1  = (const float*)d_in[11];
    const float* b_fc1  = (const float*)d_in[12];
    const float* w_fc2  = (const float*)d_in[13];
    const float* b_fc2  = (const float*)d_in[14];

    char* ws = (char*)d_ws;
    size_t off = 0;
    auto alloc = [&](size_t bytes) { void* p = ws + off; off += (bytes + 255) & ~(size_t)255; return p; };
    short* qkv_h          = (short*)alloc((size_t)NROWS * 2048 * 2);   // qkv (1536 cols), then MLP hidden (2048 cols)
    float* XALL           = (float*)alloc((size_t)NROWS * 512 * 4);    // attn + residual, f32
    short* xn             = (short*)alloc((size_t)NROWS * 512 * 2);    // LN output, bf16 (reused LN1/LN2)
    unsigned short* Wqkv_t = (unsigned short*)alloc((size_t)1536 * 512 * 2);
    unsigned short* Wfc1_t = (unsigned short*)alloc((size_t)2048 * 512 * 2);
    unsigned short* Wfc2_t = (unsigned short*)alloc((size_t)512 * 2048 * 2);
    float* bqkv           = (float*)alloc(1536 * 4);
    float* bias_exp       = (float*)alloc((size_t)NHEAD * 36 * 37 * 4);

    const int MB = (NROWS + 127) / 128;        // 289 M-tiles

    // 1. prep: weight transposes || bias/rel-bias pack || LN1 (one dispatch)
    prep_kernel<<<TPOSE_BLKS + SPACK_BLKS + LN1_BLKS, 256, 0, stream>>>(
        w_q, w_kv, w_fc1, w_fc2, Wqkv_t, Wfc1_t, Wfc2_t,
        b_q, b_kv, rel, bqkv, bias_exp,
        x, xavg, g1, be1, (unsigned short*)xn);
    // 2. QKV GEMM: [36880,512] x [512,1536] -> qkv bf16 (LDS epilogue)
    gemm_kernel<false, true, false, true><<<12 * MB, 256, 0, stream>>>(
        xn, (const short*)Wqkv_t, bqkv, qkv_h, nullptr, NROWS, 1536, 512, 12);
    // 3. MFMA windowed attention || global-token attention (+ residual) -> XALL
    attn_kernel<<<4096 + 256, 256, 0, stream>>>(qkv_h, bias_exp, x, xavg, XALL);
    // 4. LN2 -> xn (bf16)
    ln_kernel<<<(NROWS + 3) / 4, 256, 0, stream>>>(XALL, g2, be2, (unsigned short*)xn, NROWS);
    // 5. FC1 + GELU: [36880,512] x [512,2048] -> hidden bf16 (LDS epilogue)
    gemm_kernel<true, true, false, true><<<16 * MB, 256, 0, stream>>>(
        xn, (const short*)Wfc1_t, b_fc1, qkv_h, nullptr, NROWS, 2048, 512, 16);
    // 6. FC2 + bias + residual: [36880,2048] x [2048,512] -> d_out f32 (direct epilogue)
    gemm_kernel<false, false, true, false><<<4 * MB, 256, 0, stream>>>(
        qkv_h, (const short*)Wfc2_t, b_fc2, d_out, XALL, NROWS, 512, 2048, 4);
}